// Round 4
// baseline (14792.754 us; speedup 1.0000x reference)
//
#include <hip/hip_runtime.h>
#include <math.h>

#define HID 51
#define TMAIN 1024
#define FUT 64
#define TT (TMAIN + FUT)

__device__ __forceinline__ float fast_sigmoid(float x) {
  return 1.0f / (1.0f + __expf(-x));
}
__device__ __forceinline__ float fast_tanh(float x) {
  // stable both directions: x>>0 -> 1, x<<0 -> -1
  return 1.0f - 2.0f / (__expf(2.0f * x) + 1.0f);
}

// acc[g] += sum_k w[g][k] * hbuf[k], k = 0..50. hbuf is 16B-aligned LDS.
// Two partial chains per gate (q<6 / q>=6) halve the dependent-FMA latency.
__device__ __forceinline__ void dot2(const float* hbuf,
                                     const float (&w)[2][HID],
                                     float (&acc)[2]) {
  const float4* h4 = reinterpret_cast<const float4*>(hbuf);
  float accB[2] = {0.f, 0.f};
#pragma unroll
  for (int q = 0; q < 6; ++q) {
    float4 hv = h4[q];
#pragma unroll
    for (int g = 0; g < 2; ++g) {
      acc[g] = fmaf(hv.x, w[g][4 * q + 0], acc[g]);
      acc[g] = fmaf(hv.y, w[g][4 * q + 1], acc[g]);
      acc[g] = fmaf(hv.z, w[g][4 * q + 2], acc[g]);
      acc[g] = fmaf(hv.w, w[g][4 * q + 3], acc[g]);
    }
  }
#pragma unroll
  for (int q = 6; q < 12; ++q) {
    float4 hv = h4[q];
#pragma unroll
    for (int g = 0; g < 2; ++g) {
      accB[g] = fmaf(hv.x, w[g][4 * q + 0], accB[g]);
      accB[g] = fmaf(hv.y, w[g][4 * q + 1], accB[g]);
      accB[g] = fmaf(hv.z, w[g][4 * q + 2], accB[g]);
      accB[g] = fmaf(hv.w, w[g][4 * q + 3], accB[g]);
    }
  }
  float h48 = hbuf[48], h49 = hbuf[49], h50 = hbuf[50];
#pragma unroll
  for (int g = 0; g < 2; ++g) {
    accB[g] = fmaf(h48, w[g][48], accB[g]);
    accB[g] = fmaf(h49, w[g][49], accB[g]);
    accB[g] = fmaf(h50, w[g][50], accB[g]);
    acc[g] += accB[g];
  }
}

// R3 lesson: dur is invariant (3.26-3.40ms) across VGPR 68/88/128, pin or
// no pin, cap 170/256 -> NOT issue- or residency-bound. OccupancyPercent
// 18.2% == exactly one 6-wave block per CU: 512 blocks ran in TWO passes.
// Fix: pack 2 sequences per block (two independent 6-wave clusters, 768
// threads) -> 256 blocks = 1 block/CU = ONE pass. Cluster layout within
// each 6-wave group is unchanged:
//   waves 0,1: Wh1 (L1) units [0,26)/[26,51); half 0 = gates {i,f},
//              half 1 = {g,o}; recombine via __shfl_xor(32).
//   waves 2,3: Wh2 partial (L2 recurrent) -> lds_p2
//   waves 4,5: Wi2 + p2 -> L2 cell -> h2, linear head
__global__ __launch_bounds__(768, 2)
void lstm2_persistent(const float* __restrict__ input,
                      const float* __restrict__ Wi1,
                      const float* __restrict__ Wh1,
                      const float* __restrict__ bi1,
                      const float* __restrict__ bh1,
                      const float* __restrict__ Wi2,
                      const float* __restrict__ Wh2,
                      const float* __restrict__ bi2,
                      const float* __restrict__ bh2,
                      const float* __restrict__ Wlin,
                      const float* __restrict__ blin,
                      float* __restrict__ out) {
  __shared__ __align__(16) float lds_x[2][TMAIN];
  __shared__ __align__(16) float lds_h1[2][2][64];  // [cluster][parity][unit]
  __shared__ __align__(16) float lds_h2[2][64];
  __shared__ __align__(16) float lds_p2[2][4][64];
  __shared__ float lds_lin[2][2];

  const int tid = threadIdx.x;
  const int cl = (tid >= 384) ? 1 : 0;  // cluster = which sequence
  const int ltid = tid - cl * 384;
  const int s = blockIdx.x * 2 + cl;  // sequence index
  const int wid = ltid >> 6;          // 0..5 within cluster
  const int lane = ltid & 63;
  const int half = lane >> 5;   // 0: gates {i,f}, 1: gates {g,o}
  const int l5 = lane & 31;
  const int base = (wid & 1) * 26;
  const int nu = (wid & 1) ? 25 : 26;
  const bool act = l5 < nu;
  const int u = base + (act ? l5 : 0);  // clamped unit index
  const int g0 = half * 2;

  // Stage this cluster's sequence into LDS (coalesced per 384-thread group).
  for (int i = ltid; i < TMAIN; i += 384) lds_x[cl][i] = input[s * TMAIN + i];
  if (ltid < 64) {
    lds_h1[cl][0][ltid] = 0.0f;
    lds_h1[cl][1][ltid] = 0.0f;
    lds_h2[cl][ltid] = 0.0f;
  }

  // ---- Load this lane's 2 weight rows into registers ----
  float w[2][HID];
  float bias[2] = {0.f, 0.f};
  float wi1g[2] = {0.f, 0.f};
  float wlin_u = 0.0f;
  float c_state = 0.0f;

  const float* Wsel = (wid < 2) ? Wh1 : ((wid < 4) ? Wh2 : Wi2);
#pragma unroll
  for (int g = 0; g < 2; ++g) {
    const float* row = Wsel + ((g0 + g) * HID + u) * HID;
#pragma unroll
    for (int k = 0; k < HID; ++k) w[g][k] = row[k];
  }
  if (wid < 2) {
#pragma unroll
    for (int g = 0; g < 2; ++g) {
      bias[g] = bi1[(g0 + g) * HID + u] + bh1[(g0 + g) * HID + u];
      wi1g[g] = Wi1[(g0 + g) * HID + u];
    }
  } else if (wid >= 4) {
#pragma unroll
    for (int g = 0; g < 2; ++g)
      bias[g] = bi2[(g0 + g) * HID + u] + bh2[(g0 + g) * HID + u];
    wlin_u = Wlin[u];
  }
  const float blin_s = blin[0];

  __syncthreads();

  for (int t = 0; t <= TT; ++t) {
    const int pr = t & 1;  // h1 read buffer parity

    // ---- emit previous step's linear output; compute L1 input x ----
    float x = 0.0f;
    if (wid < 2) {
      float o_prev = 0.0f;
      if (t > 0) {
        o_prev = lds_lin[cl][0] + lds_lin[cl][1] + blin_s;  // from t-1
        if (wid == 0 && lane == 63) out[s * TT + (t - 1)] = o_prev;
      }
      x = (t < TMAIN) ? lds_x[cl][t] : o_prev;  // feedback in future phase
    }
    if (t == TT) break;  // final flush iteration: emit only

    // ---------------- phase 1 ----------------
    if (wid < 2) {
      // layer-1: acc = x*Wi1 + bias + Wh1 @ h1_prev (this half's 2 gates)
      float acc[2];
#pragma unroll
      for (int g = 0; g < 2; ++g) acc[g] = fmaf(x, wi1g[g], bias[g]);
      dot2(lds_h1[cl][pr], w, acc);
      // recombine gate pairs across lane halves (both halves get all 4)
      float p0 = __shfl_xor(acc[0], 32);
      float p1 = __shfl_xor(acc[1], 32);
      float gi = half ? p0 : acc[0];
      float gf = half ? p1 : acc[1];
      float gg = half ? acc[0] : p0;
      float go = half ? acc[1] : p1;
      c_state = fast_sigmoid(gf) * c_state + fast_sigmoid(gi) * fast_tanh(gg);
      float h = fast_sigmoid(go) * fast_tanh(c_state);
      if (act && half == 0) lds_h1[cl][pr ^ 1][u] = h;  // write NEW buffer
    } else if (wid < 4) {
      // layer-2 recurrent partial: Wh2 @ h2_prev (this half's 2 gates)
      float acc[2] = {0.f, 0.f};
      dot2(lds_h2[cl], w, acc);
      if (act) {
        lds_p2[cl][g0 + 0][u] = acc[0];
        lds_p2[cl][g0 + 1][u] = acc[1];
      }
    }
    __syncthreads();  // h1_new + p2 visible

    // ---------------- phase 2 ----------------
    if (wid >= 4) {
      float acc[2];
      acc[0] = bias[0] + lds_p2[cl][g0 + 0][u];
      acc[1] = bias[1] + lds_p2[cl][g0 + 1][u];
      dot2(lds_h1[cl][pr ^ 1], w, acc);  // Wi2 @ h1_new
      float p0 = __shfl_xor(acc[0], 32);
      float p1 = __shfl_xor(acc[1], 32);
      float gi = half ? p0 : acc[0];
      float gf = half ? p1 : acc[1];
      float gg = half ? acc[0] : p0;
      float go = half ? acc[1] : p1;
      c_state = fast_sigmoid(gf) * c_state + fast_sigmoid(gi) * fast_tanh(gg);
      float h = fast_sigmoid(go) * fast_tanh(c_state);
      float val = 0.0f;
      if (act && half == 0) {
        lds_h2[cl][u] = h;
        val = wlin_u * h;
      }
      // linear head: only lanes 0..25 hold nonzero vals -> butterfly over
      // the lower 32 lanes (offsets 16..1); lane 0 gets the partial sum.
#pragma unroll
      for (int off = 16; off >= 1; off >>= 1) val += __shfl_xor(val, off);
      if (lane == 0) lds_lin[cl][wid - 4] = val;  // emitted next iter
    }
    __syncthreads();  // h2_new + lin partials visible for next timestep
  }
}

extern "C" void kernel_launch(void* const* d_in, const int* in_sizes, int n_in,
                              void* d_out, int out_size, void* d_ws,
                              size_t ws_size, hipStream_t stream) {
  const float* input = (const float*)d_in[0];
  const float* Wi1 = (const float*)d_in[1];
  const float* Wh1 = (const float*)d_in[2];
  const float* bi1 = (const float*)d_in[3];
  const float* bh1 = (const float*)d_in[4];
  const float* Wi2 = (const float*)d_in[5];
  const float* Wh2 = (const float*)d_in[6];
  const float* bi2 = (const float*)d_in[7];
  const float* bh2 = (const float*)d_in[8];
  const float* Wlin = (const float*)d_in[9];
  const float* blin = (const float*)d_in[10];
  float* out = (float*)d_out;

  const int B = in_sizes[0] / TMAIN;  // 512
  lstm2_persistent<<<B / 2, 768, 0, stream>>>(input, Wi1, Wh1, bi1, bh1, Wi2,
                                              Wh2, bi2, bh2, Wlin, blin, out);
}

// Round 5
// 2628.344 us; speedup vs baseline: 5.6282x; 5.6282x over previous
//
#include <hip/hip_runtime.h>
#include <math.h>

#define HID 51
#define TMAIN 1024
#define FUT 64
#define TT (TMAIN + FUT)

__device__ __forceinline__ float fast_sigmoid(float x) {
  return 1.0f / (1.0f + __expf(-x));
}
__device__ __forceinline__ float fast_tanh(float x) {
  // stable both directions: x>>0 -> 1, x<<0 -> -1
  return 1.0f - 2.0f / (__expf(2.0f * x) + 1.0f);
}

// Dual-sequence dot: acc{A,B}[g] += sum_k w[g][k] * h{A,B}[k].
// 4 independent FMA chains (2 seqs x 2 gates) hide the 4-cy FMA latency.
__device__ __forceinline__ void dot2x(const float* hA, const float* hB,
                                      const float (&w)[2][HID],
                                      float (&aA)[2], float (&aB)[2]) {
  const float4* a4 = reinterpret_cast<const float4*>(hA);
  const float4* b4 = reinterpret_cast<const float4*>(hB);
#pragma unroll
  for (int q = 0; q < 12; ++q) {
    float4 av = a4[q];
    float4 bv = b4[q];
#pragma unroll
    for (int g = 0; g < 2; ++g) {
      aA[g] = fmaf(av.x, w[g][4 * q + 0], aA[g]);
      aB[g] = fmaf(bv.x, w[g][4 * q + 0], aB[g]);
      aA[g] = fmaf(av.y, w[g][4 * q + 1], aA[g]);
      aB[g] = fmaf(bv.y, w[g][4 * q + 1], aB[g]);
      aA[g] = fmaf(av.z, w[g][4 * q + 2], aA[g]);
      aB[g] = fmaf(bv.z, w[g][4 * q + 2], aB[g]);
      aA[g] = fmaf(av.w, w[g][4 * q + 3], aA[g]);
      aB[g] = fmaf(bv.w, w[g][4 * q + 3], aB[g]);
    }
  }
  float a48 = hA[48], a49 = hA[49], a50 = hA[50];
  float b48 = hB[48], b49 = hB[49], b50 = hB[50];
#pragma unroll
  for (int g = 0; g < 2; ++g) {
    aA[g] = fmaf(a48, w[g][48], aA[g]);
    aB[g] = fmaf(b48, w[g][48], aB[g]);
    aA[g] = fmaf(a49, w[g][49], aA[g]);
    aB[g] = fmaf(b49, w[g][49], aB[g]);
    aA[g] = fmaf(a50, w[g][50], aA[g]);
    aB[g] = fmaf(b50, w[g][50], aB[g]);
  }
}

// One block = TWO sequences, 6 waves, weights SHARED across sequences:
//   waves 0,1: Wh1 (L1) units [0,26)/[26,51); half 0 = gates {i,f},
//              half 1 = {g,o}; recombine via __shfl_xor(32).
//   waves 2,3: Wh2 partial (L2 recurrent) -> lds_p2 (both seqs)
//   waves 4,5: Wi2 + p2 -> L2 cell -> h2, linear head (both seqs)
// Model from R0-R4: unified-file usage (~102 weight values in AGPR/VGPR)
// means only ONE 6-wave block is resident per CU, so 512 single-seq
// blocks ran in TWO passes, latency-bound (VALUBusy ~30%). Two seqs per
// block -> 256 blocks = one pass, and each wave's dot has 4 independent
// chains -> FMA latency hidden. R4 lesson: keep 384 threads; 768-thread
// blocks made the allocator spill the weights to scratch (35 GB FETCH).
__global__ __launch_bounds__(384, 2)
void lstm2_persistent(const float* __restrict__ input,
                      const float* __restrict__ Wi1,
                      const float* __restrict__ Wh1,
                      const float* __restrict__ bi1,
                      const float* __restrict__ bh1,
                      const float* __restrict__ Wi2,
                      const float* __restrict__ Wh2,
                      const float* __restrict__ bi2,
                      const float* __restrict__ bh2,
                      const float* __restrict__ Wlin,
                      const float* __restrict__ blin,
                      float* __restrict__ out) {
  __shared__ __align__(16) float lds_x[2][TMAIN];      // [seq][t]
  __shared__ __align__(16) float lds_h1[2][2][64];     // [seq][parity][unit]
  __shared__ __align__(16) float lds_h2[2][64];        // [seq][unit]
  __shared__ __align__(16) float lds_p2[2][4][64];     // [seq][gate][unit]
  __shared__ float lds_lin[2][2];                      // [seq][wavehalf]

  const int tid = threadIdx.x;
  const int s0 = blockIdx.x * 2;  // sequence pair
  const int wid = tid >> 6;       // 0..5
  const int lane = tid & 63;
  const int half = lane >> 5;   // 0: gates {i,f}, 1: gates {g,o}
  const int l5 = lane & 31;
  const int base = (wid & 1) * 26;
  const int nu = (wid & 1) ? 25 : 26;
  const bool act = l5 < nu;
  const int u = base + (act ? l5 : 0);  // clamped unit index
  const int g0 = half * 2;

  // Stage both sequences' inputs into LDS (coalesced).
  for (int i = tid; i < TMAIN; i += 384) {
    lds_x[0][i] = input[s0 * TMAIN + i];
    lds_x[1][i] = input[(s0 + 1) * TMAIN + i];
  }
  if (tid < 64) {
    lds_h1[0][0][tid] = 0.0f;
    lds_h1[0][1][tid] = 0.0f;
    lds_h1[1][0][tid] = 0.0f;
    lds_h1[1][1][tid] = 0.0f;
    lds_h2[0][tid] = 0.0f;
    lds_h2[1][tid] = 0.0f;
  }

  // ---- Load this lane's 2 weight rows (shared by both sequences) ----
  float w[2][HID];
  float bias[2] = {0.f, 0.f};
  float wi1g[2] = {0.f, 0.f};
  float wlin_u = 0.0f;
  float cA = 0.0f, cB = 0.0f;  // cell states for seq A / B

  const float* Wsel = (wid < 2) ? Wh1 : ((wid < 4) ? Wh2 : Wi2);
#pragma unroll
  for (int g = 0; g < 2; ++g) {
    const float* row = Wsel + ((g0 + g) * HID + u) * HID;
#pragma unroll
    for (int k = 0; k < HID; ++k) w[g][k] = row[k];
  }
  if (wid < 2) {
#pragma unroll
    for (int g = 0; g < 2; ++g) {
      bias[g] = bi1[(g0 + g) * HID + u] + bh1[(g0 + g) * HID + u];
      wi1g[g] = Wi1[(g0 + g) * HID + u];
    }
  } else if (wid >= 4) {
#pragma unroll
    for (int g = 0; g < 2; ++g)
      bias[g] = bi2[(g0 + g) * HID + u] + bh2[(g0 + g) * HID + u];
    wlin_u = Wlin[u];
  }
  const float blin_s = blin[0];

  // ---- PIN: opaque asm defs prevent remat of the invariant weight loads.
#pragma unroll
  for (int g = 0; g < 2; ++g) {
#pragma unroll
    for (int k = 0; k < HID; ++k) asm volatile("" : "+v"(w[g][k]));
    asm volatile("" : "+v"(bias[g]), "+v"(wi1g[g]));
  }
  asm volatile("" : "+v"(wlin_u));

  __syncthreads();

  for (int t = 0; t <= TT; ++t) {
    const int pr = t & 1;  // h1 read buffer parity

    // ---- emit previous step's outputs; compute L1 inputs xA, xB ----
    float xA = 0.0f, xB = 0.0f;
    if (wid < 2) {
      float oA = 0.0f, oB = 0.0f;
      if (t > 0) {
        oA = lds_lin[0][0] + lds_lin[0][1] + blin_s;
        oB = lds_lin[1][0] + lds_lin[1][1] + blin_s;
        if (lane == 63) {
          if (wid == 0) out[s0 * TT + (t - 1)] = oA;
          else          out[(s0 + 1) * TT + (t - 1)] = oB;
        }
      }
      xA = (t < TMAIN) ? lds_x[0][t] : oA;
      xB = (t < TMAIN) ? lds_x[1][t] : oB;
    }
    if (t == TT) break;  // final flush iteration: emit only

    // ---------------- phase 1 ----------------
    if (wid < 2) {
      // layer-1 for both seqs: acc = x*Wi1 + bias + Wh1 @ h1_prev
      float aA[2], aB[2];
#pragma unroll
      for (int g = 0; g < 2; ++g) {
        aA[g] = fmaf(xA, wi1g[g], bias[g]);
        aB[g] = fmaf(xB, wi1g[g], bias[g]);
      }
      dot2x(lds_h1[0][pr], lds_h1[1][pr], w, aA, aB);
      float pA0 = __shfl_xor(aA[0], 32);
      float pA1 = __shfl_xor(aA[1], 32);
      float pB0 = __shfl_xor(aB[0], 32);
      float pB1 = __shfl_xor(aB[1], 32);
      float giA = half ? pA0 : aA[0], gfA = half ? pA1 : aA[1];
      float ggA = half ? aA[0] : pA0, goA = half ? aA[1] : pA1;
      float giB = half ? pB0 : aB[0], gfB = half ? pB1 : aB[1];
      float ggB = half ? aB[0] : pB0, goB = half ? aB[1] : pB1;
      cA = fast_sigmoid(gfA) * cA + fast_sigmoid(giA) * fast_tanh(ggA);
      cB = fast_sigmoid(gfB) * cB + fast_sigmoid(giB) * fast_tanh(ggB);
      float hA = fast_sigmoid(goA) * fast_tanh(cA);
      float hB = fast_sigmoid(goB) * fast_tanh(cB);
      if (act && half == 0) {
        lds_h1[0][pr ^ 1][u] = hA;
        lds_h1[1][pr ^ 1][u] = hB;
      }
    } else if (wid < 4) {
      // layer-2 recurrent partials for both seqs: Wh2 @ h2_prev
      float aA[2] = {0.f, 0.f}, aB[2] = {0.f, 0.f};
      dot2x(lds_h2[0], lds_h2[1], w, aA, aB);
      if (act) {
        lds_p2[0][g0 + 0][u] = aA[0];
        lds_p2[0][g0 + 1][u] = aA[1];
        lds_p2[1][g0 + 0][u] = aB[0];
        lds_p2[1][g0 + 1][u] = aB[1];
      }
    }
    __syncthreads();  // h1_new + p2 visible

    // ---------------- phase 2 ----------------
    if (wid >= 4) {
      float aA[2], aB[2];
      aA[0] = bias[0] + lds_p2[0][g0 + 0][u];
      aA[1] = bias[1] + lds_p2[0][g0 + 1][u];
      aB[0] = bias[0] + lds_p2[1][g0 + 0][u];
      aB[1] = bias[1] + lds_p2[1][g0 + 1][u];
      dot2x(lds_h1[0][pr ^ 1], lds_h1[1][pr ^ 1], w, aA, aB);  // Wi2 @ h1_new
      float pA0 = __shfl_xor(aA[0], 32);
      float pA1 = __shfl_xor(aA[1], 32);
      float pB0 = __shfl_xor(aB[0], 32);
      float pB1 = __shfl_xor(aB[1], 32);
      float giA = half ? pA0 : aA[0], gfA = half ? pA1 : aA[1];
      float ggA = half ? aA[0] : pA0, goA = half ? aA[1] : pA1;
      float giB = half ? pB0 : aB[0], gfB = half ? pB1 : aB[1];
      float ggB = half ? aB[0] : pB0, goB = half ? aB[1] : pB1;
      cA = fast_sigmoid(gfA) * cA + fast_sigmoid(giA) * fast_tanh(ggA);
      cB = fast_sigmoid(gfB) * cB + fast_sigmoid(giB) * fast_tanh(ggB);
      float hA = fast_sigmoid(goA) * fast_tanh(cA);
      float hB = fast_sigmoid(goB) * fast_tanh(cB);
      // half 0 lanes own seq A's reduction, half 1 lanes own seq B's.
      float val = 0.0f;
      if (act) {
        if (half == 0) {
          lds_h2[0][u] = hA;
          val = wlin_u * hA;
        } else {
          lds_h2[1][u] = hB;
          val = wlin_u * hB;
        }
      }
      // butterfly over offsets 16..1 keeps the two 32-lane halves separate
#pragma unroll
      for (int off = 16; off >= 1; off >>= 1) val += __shfl_xor(val, off);
      if (lane == 0) lds_lin[0][wid - 4] = val;
      if (lane == 32) lds_lin[1][wid - 4] = val;
    }
    __syncthreads();  // h2_new + lin partials visible for next timestep
  }
}

extern "C" void kernel_launch(void* const* d_in, const int* in_sizes, int n_in,
                              void* d_out, int out_size, void* d_ws,
                              size_t ws_size, hipStream_t stream) {
  const float* input = (const float*)d_in[0];
  const float* Wi1 = (const float*)d_in[1];
  const float* Wh1 = (const float*)d_in[2];
  const float* bi1 = (const float*)d_in[3];
  const float* bh1 = (const float*)d_in[4];
  const float* Wi2 = (const float*)d_in[5];
  const float* Wh2 = (const float*)d_in[6];
  const float* bi2 = (const float*)d_in[7];
  const float* bh2 = (const float*)d_in[8];
  const float* Wlin = (const float*)d_in[9];
  const float* blin = (const float*)d_in[10];
  float* out = (float*)d_out;

  const int B = in_sizes[0] / TMAIN;  // 512
  lstm2_persistent<<<B / 2, 384, 0, stream>>>(input, Wi1, Wh1, bi1, bh1, Wi2,
                                              Wh2, bi2, bh2, Wlin, blin, out);
}

// Round 6
// 1826.920 us; speedup vs baseline: 8.0971x; 1.4387x over previous
//
#include <hip/hip_runtime.h>
#include <math.h>

#define HID 51
#define TMAIN 1024
#define FUT 64
#define TT (TMAIN + FUT)

__device__ __forceinline__ float fast_sigmoid(float x) {
  return 1.0f / (1.0f + __expf(-x));
}
__device__ __forceinline__ float fast_tanh(float x) {
  // stable both directions: x>>0 -> 1, x<<0 -> -1
  return 1.0f - 2.0f / (__expf(2.0f * x) + 1.0f);
}

// Dual-sequence dot: acc{A,B}[g] += sum_k w[g][k] * h{A,B}[k].
// 4 independent FMA chains (2 seqs x 2 gates) hide the 4-cy FMA latency.
__device__ __forceinline__ void dot2x(const float* hA, const float* hB,
                                      const float (&w)[2][HID],
                                      float (&aA)[2], float (&aB)[2]) {
  const float4* a4 = reinterpret_cast<const float4*>(hA);
  const float4* b4 = reinterpret_cast<const float4*>(hB);
#pragma unroll
  for (int q = 0; q < 12; ++q) {
    float4 av = a4[q];
    float4 bv = b4[q];
#pragma unroll
    for (int g = 0; g < 2; ++g) {
      aA[g] = fmaf(av.x, w[g][4 * q + 0], aA[g]);
      aB[g] = fmaf(bv.x, w[g][4 * q + 0], aB[g]);
      aA[g] = fmaf(av.y, w[g][4 * q + 1], aA[g]);
      aB[g] = fmaf(bv.y, w[g][4 * q + 1], aB[g]);
      aA[g] = fmaf(av.z, w[g][4 * q + 2], aA[g]);
      aB[g] = fmaf(bv.z, w[g][4 * q + 2], aB[g]);
      aA[g] = fmaf(av.w, w[g][4 * q + 3], aA[g]);
      aB[g] = fmaf(bv.w, w[g][4 * q + 3], aB[g]);
    }
  }
  float a48 = hA[48], a49 = hA[49], a50 = hA[50];
  float b48 = hB[48], b49 = hB[49], b50 = hB[50];
#pragma unroll
  for (int g = 0; g < 2; ++g) {
    aA[g] = fmaf(a48, w[g][48], aA[g]);
    aB[g] = fmaf(b48, w[g][48], aB[g]);
    aA[g] = fmaf(a49, w[g][49], aA[g]);
    aB[g] = fmaf(b49, w[g][49], aB[g]);
    aA[g] = fmaf(a50, w[g][50], aA[g]);
    aB[g] = fmaf(b50, w[g][50], aB[g]);
  }
}

// One block = TWO sequences, 6 waves, weights shared across sequences.
// R5 lesson: 2-phase-serial steps are latency-bound (VALUBusy 36%, step
// ~5.9k cyc). This version SOFTWARE-PIPELINES the layers (L2 skewed 2
// steps behind L1) so all 6 waves work every interval with ONE barrier:
//   interval k:
//     waves 0,1 (Wh1+b1):  h1(k)   = cell1(x(k), h1(k-1))
//     waves 2,3 (Wi2+b2):  pi(k-1) = Wi2 @ h1(k-1) + b2
//     waves 4,5 (Wh2+wlin):h2(k-2) = cell2(pi(k-2) + Wh2 @ h2(k-3)), lin
// Parity double-buffers (value m lives in buffer m&1) eliminate races.
// Feedback phase (t>=TMAIN, out->x collapses the skew) runs a 3-sub-phase
// serial schedule for the 64 future steps.
// Unit split: wid&1 -> units [0,26)/[26,51). Lane-half -> gate pair
// ({i,f} / {g,o}), recombined via __shfl_xor(32).
__global__ __launch_bounds__(384, 2)
void lstm2_persistent(const float* __restrict__ input,
                      const float* __restrict__ Wi1,
                      const float* __restrict__ Wh1,
                      const float* __restrict__ bi1,
                      const float* __restrict__ bh1,
                      const float* __restrict__ Wi2,
                      const float* __restrict__ Wh2,
                      const float* __restrict__ bi2,
                      const float* __restrict__ bh2,
                      const float* __restrict__ Wlin,
                      const float* __restrict__ blin,
                      float* __restrict__ out) {
  __shared__ __align__(16) float lds_x[2][TMAIN];       // [seq][t]
  __shared__ __align__(16) float lds_h1[2][2][64];      // [seq][parity][unit]
  __shared__ __align__(16) float lds_h2[2][2][64];      // [seq][parity][unit]
  __shared__ __align__(16) float lds_pi[2][2][4][64];   // [parity][seq][gate][u]
  __shared__ float lds_lin[2][2][2];                    // [parity][seq][wavehalf]

  const int tid = threadIdx.x;
  const int s0 = blockIdx.x * 2;  // sequence pair
  const int wid = tid >> 6;       // 0..5
  const int lane = tid & 63;
  const int half = lane >> 5;   // 0: gates {i,f}, 1: gates {g,o}
  const int l5 = lane & 31;
  const int base = (wid & 1) * 26;
  const int nu = (wid & 1) ? 25 : 26;
  const bool act = l5 < nu;
  const int u = base + (act ? l5 : 0);  // clamped unit index
  const int g0 = half * 2;

  // Stage both sequences' inputs into LDS (coalesced).
  for (int i = tid; i < TMAIN; i += 384) {
    lds_x[0][i] = input[s0 * TMAIN + i];
    lds_x[1][i] = input[(s0 + 1) * TMAIN + i];
  }
  if (tid < 64) {
#pragma unroll
    for (int p = 0; p < 2; ++p) {
      lds_h1[0][p][tid] = 0.0f;
      lds_h1[1][p][tid] = 0.0f;
      lds_h2[0][p][tid] = 0.0f;
      lds_h2[1][p][tid] = 0.0f;
    }
  }

  // ---- Load this lane's 2 weight rows (shared by both sequences) ----
  float w[2][HID];
  float bias[2] = {0.f, 0.f};
  float wi1g[2] = {0.f, 0.f};
  float wlin_u = 0.0f;
  float cA = 0.0f, cB = 0.0f;  // cell states (L1 for waves01, L2 for waves45)

  const float* Wsel = (wid < 2) ? Wh1 : ((wid < 4) ? Wi2 : Wh2);
#pragma unroll
  for (int g = 0; g < 2; ++g) {
    const float* row = Wsel + ((g0 + g) * HID + u) * HID;
#pragma unroll
    for (int k = 0; k < HID; ++k) w[g][k] = row[k];
  }
  if (wid < 2) {
#pragma unroll
    for (int g = 0; g < 2; ++g) {
      bias[g] = bi1[(g0 + g) * HID + u] + bh1[(g0 + g) * HID + u];
      wi1g[g] = Wi1[(g0 + g) * HID + u];
    }
  } else if (wid < 4) {
#pragma unroll
    for (int g = 0; g < 2; ++g)
      bias[g] = bi2[(g0 + g) * HID + u] + bh2[(g0 + g) * HID + u];
  } else {
    wlin_u = Wlin[u];
  }
  const float blin_s = blin[0];

  // ---- PIN: opaque asm defs prevent remat of the invariant weight loads.
#pragma unroll
  for (int g = 0; g < 2; ++g) {
#pragma unroll
    for (int k = 0; k < HID; ++k) asm volatile("" : "+v"(w[g][k]));
    asm volatile("" : "+v"(bias[g]), "+v"(wi1g[g]));
  }
  asm volatile("" : "+v"(wlin_u));

  __syncthreads();

  // =============== main-phase pipeline: one barrier per interval ========
  for (int k = 0; k <= TMAIN + 1; ++k) {
    if (wid < 2) {
      // store out(k-3) (lin partials written by waves45 at interval k-1)
      if (k >= 3 && lane == 63) {
        const int m = k - 3;
        const int sq = wid;
        float o = lds_lin[m & 1][sq][0] + lds_lin[m & 1][sq][1] + blin_s;
        out[(s0 + sq) * TT + m] = o;
      }
      if (k < TMAIN) {
        // h1(k) = cell1(x(k), h1(k-1));  h1(m) lives in buffer (m+1)&1
        float xA = lds_x[0][k], xB = lds_x[1][k];
        float aA[2], aB[2];
#pragma unroll
        for (int g = 0; g < 2; ++g) {
          aA[g] = fmaf(xA, wi1g[g], bias[g]);
          aB[g] = fmaf(xB, wi1g[g], bias[g]);
        }
        dot2x(lds_h1[0][k & 1], lds_h1[1][k & 1], w, aA, aB);
        float pA0 = __shfl_xor(aA[0], 32), pA1 = __shfl_xor(aA[1], 32);
        float pB0 = __shfl_xor(aB[0], 32), pB1 = __shfl_xor(aB[1], 32);
        float giA = half ? pA0 : aA[0], gfA = half ? pA1 : aA[1];
        float ggA = half ? aA[0] : pA0, goA = half ? aA[1] : pA1;
        float giB = half ? pB0 : aB[0], gfB = half ? pB1 : aB[1];
        float ggB = half ? aB[0] : pB0, goB = half ? aB[1] : pB1;
        cA = fast_sigmoid(gfA) * cA + fast_sigmoid(giA) * fast_tanh(ggA);
        cB = fast_sigmoid(gfB) * cB + fast_sigmoid(giB) * fast_tanh(ggB);
        float hA = fast_sigmoid(goA) * fast_tanh(cA);
        float hB = fast_sigmoid(goB) * fast_tanh(cB);
        if (act && half == 0) {
          lds_h1[0][(k + 1) & 1][u] = hA;
          lds_h1[1][(k + 1) & 1][u] = hB;
        }
      }
    } else if (wid < 4) {
      if (k >= 1 && k <= TMAIN) {
        // pi(k-1) = Wi2 @ h1(k-1) + b2   (h1(k-1) in buffer k&1)
        float aA[2] = {bias[0], bias[1]}, aB[2] = {bias[0], bias[1]};
        dot2x(lds_h1[0][k & 1], lds_h1[1][k & 1], w, aA, aB);
        if (act) {
          const int pm = (k - 1) & 1;
          lds_pi[pm][0][g0 + 0][u] = aA[0];
          lds_pi[pm][0][g0 + 1][u] = aA[1];
          lds_pi[pm][1][g0 + 0][u] = aB[0];
          lds_pi[pm][1][g0 + 1][u] = aB[1];
        }
      }
    } else {
      if (k >= 2) {
        // h2(m) = cell2(pi(m) + Wh2 @ h2(m-1)), m = k-2; lin partial
        const int m = k - 2;
        float aA[2], aB[2];
        aA[0] = lds_pi[m & 1][0][g0 + 0][u];
        aA[1] = lds_pi[m & 1][0][g0 + 1][u];
        aB[0] = lds_pi[m & 1][1][g0 + 0][u];
        aB[1] = lds_pi[m & 1][1][g0 + 1][u];
        dot2x(lds_h2[0][(m - 1) & 1], lds_h2[1][(m - 1) & 1], w, aA, aB);
        float pA0 = __shfl_xor(aA[0], 32), pA1 = __shfl_xor(aA[1], 32);
        float pB0 = __shfl_xor(aB[0], 32), pB1 = __shfl_xor(aB[1], 32);
        float giA = half ? pA0 : aA[0], gfA = half ? pA1 : aA[1];
        float ggA = half ? aA[0] : pA0, goA = half ? aA[1] : pA1;
        float giB = half ? pB0 : aB[0], gfB = half ? pB1 : aB[1];
        float ggB = half ? aB[0] : pB0, goB = half ? aB[1] : pB1;
        cA = fast_sigmoid(gfA) * cA + fast_sigmoid(giA) * fast_tanh(ggA);
        cB = fast_sigmoid(gfB) * cB + fast_sigmoid(giB) * fast_tanh(ggB);
        float hA = fast_sigmoid(goA) * fast_tanh(cA);
        float hB = fast_sigmoid(goB) * fast_tanh(cB);
        float val = 0.0f;
        if (act) {
          if (half == 0) {
            lds_h2[0][m & 1][u] = hA;
            val = wlin_u * hA;
          } else {
            lds_h2[1][m & 1][u] = hB;
            val = wlin_u * hB;
          }
        }
#pragma unroll
        for (int off = 16; off >= 1; off >>= 1) val += __shfl_xor(val, off);
        if (lane == 0) lds_lin[m & 1][0][wid - 4] = val;
        if (lane == 32) lds_lin[m & 1][1][wid - 4] = val;
      }
    }
    __syncthreads();
  }

  // =============== feedback phase: 3 sub-phases, serial ================
  for (int t = TMAIN; t < TT; ++t) {
    float phA[2] = {0.f, 0.f}, phB[2] = {0.f, 0.f};
    // --- A: L1 cell with feedback x; waves45 pre-dot Wh2 @ h2(t-1) ---
    if (wid < 2) {
      float oA = lds_lin[(t - 1) & 1][0][0] + lds_lin[(t - 1) & 1][0][1] +
                 blin_s;
      float oB = lds_lin[(t - 1) & 1][1][0] + lds_lin[(t - 1) & 1][1][1] +
                 blin_s;
      if (lane == 63) {
        if (wid == 0) out[s0 * TT + (t - 1)] = oA;
        else          out[(s0 + 1) * TT + (t - 1)] = oB;
      }
      float aA[2], aB[2];
#pragma unroll
      for (int g = 0; g < 2; ++g) {
        aA[g] = fmaf(oA, wi1g[g], bias[g]);
        aB[g] = fmaf(oB, wi1g[g], bias[g]);
      }
      dot2x(lds_h1[0][t & 1], lds_h1[1][t & 1], w, aA, aB);
      float pA0 = __shfl_xor(aA[0], 32), pA1 = __shfl_xor(aA[1], 32);
      float pB0 = __shfl_xor(aB[0], 32), pB1 = __shfl_xor(aB[1], 32);
      float giA = half ? pA0 : aA[0], gfA = half ? pA1 : aA[1];
      float ggA = half ? aA[0] : pA0, goA = half ? aA[1] : pA1;
      float giB = half ? pB0 : aB[0], gfB = half ? pB1 : aB[1];
      float ggB = half ? aB[0] : pB0, goB = half ? aB[1] : pB1;
      cA = fast_sigmoid(gfA) * cA + fast_sigmoid(giA) * fast_tanh(ggA);
      cB = fast_sigmoid(gfB) * cB + fast_sigmoid(giB) * fast_tanh(ggB);
      float hA = fast_sigmoid(goA) * fast_tanh(cA);
      float hB = fast_sigmoid(goB) * fast_tanh(cB);
      if (act && half == 0) {
        lds_h1[0][(t + 1) & 1][u] = hA;
        lds_h1[1][(t + 1) & 1][u] = hB;
      }
    } else if (wid >= 4) {
      dot2x(lds_h2[0][(t - 1) & 1], lds_h2[1][(t - 1) & 1], w, phA, phB);
    }
    __syncthreads();
    // --- B: pi(t) = Wi2 @ h1(t) + b2 ---
    if (wid >= 2 && wid < 4) {
      float aA[2] = {bias[0], bias[1]}, aB[2] = {bias[0], bias[1]};
      dot2x(lds_h1[0][(t + 1) & 1], lds_h1[1][(t + 1) & 1], w, aA, aB);
      if (act) {
        const int pm = t & 1;
        lds_pi[pm][0][g0 + 0][u] = aA[0];
        lds_pi[pm][0][g0 + 1][u] = aA[1];
        lds_pi[pm][1][g0 + 0][u] = aB[0];
        lds_pi[pm][1][g0 + 1][u] = aB[1];
      }
    }
    __syncthreads();
    // --- C: L2 cell + linear head ---
    if (wid >= 4) {
      float aA[2], aB[2];
      aA[0] = lds_pi[t & 1][0][g0 + 0][u] + phA[0];
      aA[1] = lds_pi[t & 1][0][g0 + 1][u] + phA[1];
      aB[0] = lds_pi[t & 1][1][g0 + 0][u] + phB[0];
      aB[1] = lds_pi[t & 1][1][g0 + 1][u] + phB[1];
      float pA0 = __shfl_xor(aA[0], 32), pA1 = __shfl_xor(aA[1], 32);
      float pB0 = __shfl_xor(aB[0], 32), pB1 = __shfl_xor(aB[1], 32);
      float giA = half ? pA0 : aA[0], gfA = half ? pA1 : aA[1];
      float ggA = half ? aA[0] : pA0, goA = half ? aA[1] : pA1;
      float giB = half ? pB0 : aB[0], gfB = half ? pB1 : aB[1];
      float ggB = half ? aB[0] : pB0, goB = half ? aB[1] : pB1;
      cA = fast_sigmoid(gfA) * cA + fast_sigmoid(giA) * fast_tanh(ggA);
      cB = fast_sigmoid(gfB) * cB + fast_sigmoid(giB) * fast_tanh(ggB);
      float hA = fast_sigmoid(goA) * fast_tanh(cA);
      float hB = fast_sigmoid(goB) * fast_tanh(cB);
      float val = 0.0f;
      if (act) {
        if (half == 0) {
          lds_h2[0][t & 1][u] = hA;
          val = wlin_u * hA;
        } else {
          lds_h2[1][t & 1][u] = hB;
          val = wlin_u * hB;
        }
      }
#pragma unroll
      for (int off = 16; off >= 1; off >>= 1) val += __shfl_xor(val, off);
      if (lane == 0) lds_lin[t & 1][0][wid - 4] = val;
      if (lane == 32) lds_lin[t & 1][1][wid - 4] = val;
    }
    __syncthreads();
  }

  // epilogue: store out(TT-1)
  if (wid < 2 && lane == 63) {
    const int sq = wid;
    float o = lds_lin[(TT - 1) & 1][sq][0] + lds_lin[(TT - 1) & 1][sq][1] +
              blin_s;
    out[(s0 + sq) * TT + (TT - 1)] = o;
  }
}

extern "C" void kernel_launch(void* const* d_in, const int* in_sizes, int n_in,
                              void* d_out, int out_size, void* d_ws,
                              size_t ws_size, hipStream_t stream) {
  const float* input = (const float*)d_in[0];
  const float* Wi1 = (const float*)d_in[1];
  const float* Wh1 = (const float*)d_in[2];
  const float* bi1 = (const float*)d_in[3];
  const float* bh1 = (const float*)d_in[4];
  const float* Wi2 = (const float*)d_in[5];
  const float* Wh2 = (const float*)d_in[6];
  const float* bi2 = (const float*)d_in[7];
  const float* bh2 = (const float*)d_in[8];
  const float* Wlin = (const float*)d_in[9];
  const float* blin = (const float*)d_in[10];
  float* out = (float*)d_out;

  const int B = in_sizes[0] / TMAIN;  // 512
  lstm2_persistent<<<B / 2, 384, 0, stream>>>(input, Wi1, Wh1, bi1, bh1, Wi2,
                                              Wh2, bi2, bh2, Wlin, blin, out);
}

// Round 7
// 1782.449 us; speedup vs baseline: 8.2991x; 1.0249x over previous
//
#include <hip/hip_runtime.h>
#include <math.h>

#define HID 51
#define TMAIN 1024
#define FUT 64
#define TT (TMAIN + FUT)

typedef float v2f __attribute__((ext_vector_type(2)));

__device__ __forceinline__ float fast_sigmoid(float x) {
  return 1.0f / (1.0f + __expf(-x));
}
__device__ __forceinline__ float fast_tanh(float x) {
  // stable both directions: x>>0 -> 1, x<<0 -> -1
  return 1.0f - 2.0f / (__expf(2.0f * x) + 1.0f);
}

// Dual-sequence packed dot: acc{A,B}[g] += sum_k w[g][k] * h{A,B}[k].
// K consumed as float2 pairs -> v_pk_fma_f32 (2 MACs/inst, gfx90a+).
// 4 independent v2f chains (2 seqs x 2 gates): issue ~110 insts vs 208
// scalar. h read as float4 (ds_read_b128); a4[12] reads h[48..51] which
// is in-bounds of the [64] buffers (h[51] junk unused).
__device__ __forceinline__ void dot2x(const float* hA, const float* hB,
                                      const v2f (&w2)[2][25],
                                      const float (&w50)[2],
                                      float (&aA)[2], float (&aB)[2]) {
  const float4* a4 = reinterpret_cast<const float4*>(hA);
  const float4* b4 = reinterpret_cast<const float4*>(hB);
  v2f sA0 = {0.f, 0.f}, sA1 = {0.f, 0.f};
  v2f sB0 = {0.f, 0.f}, sB1 = {0.f, 0.f};
#pragma unroll
  for (int q = 0; q < 12; ++q) {
    float4 av = a4[q];
    float4 bv = b4[q];
    v2f alo = {av.x, av.y}, ahi = {av.z, av.w};
    v2f blo = {bv.x, bv.y}, bhi = {bv.z, bv.w};
    sA0 = __builtin_elementwise_fma(alo, w2[0][2 * q + 0], sA0);
    sB0 = __builtin_elementwise_fma(blo, w2[0][2 * q + 0], sB0);
    sA1 = __builtin_elementwise_fma(alo, w2[1][2 * q + 0], sA1);
    sB1 = __builtin_elementwise_fma(blo, w2[1][2 * q + 0], sB1);
    sA0 = __builtin_elementwise_fma(ahi, w2[0][2 * q + 1], sA0);
    sB0 = __builtin_elementwise_fma(bhi, w2[0][2 * q + 1], sB0);
    sA1 = __builtin_elementwise_fma(ahi, w2[1][2 * q + 1], sA1);
    sB1 = __builtin_elementwise_fma(bhi, w2[1][2 * q + 1], sB1);
  }
  // tail: pair (h48,h49) via w2[g][24], scalar h50 via w50[g]
  float4 at = a4[12];
  float4 bt = b4[12];
  v2f alo = {at.x, at.y}, blo = {bt.x, bt.y};
  sA0 = __builtin_elementwise_fma(alo, w2[0][24], sA0);
  sB0 = __builtin_elementwise_fma(blo, w2[0][24], sB0);
  sA1 = __builtin_elementwise_fma(alo, w2[1][24], sA1);
  sB1 = __builtin_elementwise_fma(blo, w2[1][24], sB1);
  aA[0] = fmaf(at.z, w50[0], aA[0] + sA0.x + sA0.y);
  aB[0] = fmaf(bt.z, w50[0], aB[0] + sB0.x + sB0.y);
  aA[1] = fmaf(at.z, w50[1], aA[1] + sA1.x + sA1.y);
  aB[1] = fmaf(bt.z, w50[1], aB[1] + sB1.x + sB1.y);
}

// One block = TWO sequences, 6 waves, weights shared across sequences.
// R6 structure (software-pipelined layers, 1 barrier/interval) kept intact:
//   interval k:
//     waves 0,1 (Wh1+b1):  h1(k)   = cell1(x(k), h1(k-1))
//     waves 2,3 (Wi2+b2):  pi(k-1) = Wi2 @ h1(k-1) + b2
//     waves 4,5 (Wh2+wlin):h2(k-2) = cell2(pi(k-2) + Wh2 @ h2(k-3)), lin
// Parity double-buffers; feedback phase = 3-sub-phase serial for 64 steps.
// R6 lesson: 6 waves land (2,2,1,1) on 4 SIMDs; the 2-wave SIMDs' ~820cy
// of scalar dot issue set the barrier pace (VALUBusy 52%). This round
// halves dot issue with v_pk_fma_f32 (packed f32, full-rate on CDNA4).
__global__ __launch_bounds__(384, 2)
void lstm2_persistent(const float* __restrict__ input,
                      const float* __restrict__ Wi1,
                      const float* __restrict__ Wh1,
                      const float* __restrict__ bi1,
                      const float* __restrict__ bh1,
                      const float* __restrict__ Wi2,
                      const float* __restrict__ Wh2,
                      const float* __restrict__ bi2,
                      const float* __restrict__ bh2,
                      const float* __restrict__ Wlin,
                      const float* __restrict__ blin,
                      float* __restrict__ out) {
  __shared__ __align__(16) float lds_x[2][TMAIN];       // [seq][t]
  __shared__ __align__(16) float lds_h1[2][2][64];      // [seq][parity][unit]
  __shared__ __align__(16) float lds_h2[2][2][64];      // [seq][parity][unit]
  __shared__ __align__(16) float lds_pi[2][2][4][64];   // [parity][seq][gate][u]
  __shared__ float lds_lin[2][2][2];                    // [parity][seq][wavehalf]

  const int tid = threadIdx.x;
  const int s0 = blockIdx.x * 2;  // sequence pair
  const int wid = tid >> 6;       // 0..5
  const int lane = tid & 63;
  const int half = lane >> 5;   // 0: gates {i,f}, 1: gates {g,o}
  const int l5 = lane & 31;
  const int base = (wid & 1) * 26;
  const int nu = (wid & 1) ? 25 : 26;
  const bool act = l5 < nu;
  const int u = base + (act ? l5 : 0);  // clamped unit index
  const int g0 = half * 2;

  // Stage both sequences' inputs into LDS (coalesced).
  for (int i = tid; i < TMAIN; i += 384) {
    lds_x[0][i] = input[s0 * TMAIN + i];
    lds_x[1][i] = input[(s0 + 1) * TMAIN + i];
  }
  if (tid < 64) {
#pragma unroll
    for (int p = 0; p < 2; ++p) {
      lds_h1[0][p][tid] = 0.0f;
      lds_h1[1][p][tid] = 0.0f;
      lds_h2[0][p][tid] = 0.0f;
      lds_h2[1][p][tid] = 0.0f;
    }
  }

  // ---- Load this lane's 2 weight rows (shared by both sequences) ----
  v2f w2[2][25];    // k=0..49 as pairs
  float w50[2];     // k=50
  float bias[2] = {0.f, 0.f};
  float wi1g[2] = {0.f, 0.f};
  float wlin_u = 0.0f;
  float cA = 0.0f, cB = 0.0f;  // cell states (L1 for waves01, L2 for waves45)

  const float* Wsel = (wid < 2) ? Wh1 : ((wid < 4) ? Wi2 : Wh2);
#pragma unroll
  for (int g = 0; g < 2; ++g) {
    const float* row = Wsel + ((g0 + g) * HID + u) * HID;
#pragma unroll
    for (int p = 0; p < 25; ++p) {
      v2f t;
      t.x = row[2 * p + 0];
      t.y = row[2 * p + 1];
      w2[g][p] = t;
    }
    w50[g] = row[50];
  }
  if (wid < 2) {
#pragma unroll
    for (int g = 0; g < 2; ++g) {
      bias[g] = bi1[(g0 + g) * HID + u] + bh1[(g0 + g) * HID + u];
      wi1g[g] = Wi1[(g0 + g) * HID + u];
    }
  } else if (wid < 4) {
#pragma unroll
    for (int g = 0; g < 2; ++g)
      bias[g] = bi2[(g0 + g) * HID + u] + bh2[(g0 + g) * HID + u];
  } else {
    wlin_u = Wlin[u];
  }
  const float blin_s = blin[0];

  // ---- PIN: opaque asm defs prevent remat of the invariant weight loads.
#pragma unroll
  for (int g = 0; g < 2; ++g) {
#pragma unroll
    for (int p = 0; p < 25; ++p) asm volatile("" : "+v"(w2[g][p]));
    asm volatile("" : "+v"(w50[g]), "+v"(bias[g]), "+v"(wi1g[g]));
  }
  asm volatile("" : "+v"(wlin_u));

  __syncthreads();

  // =============== main-phase pipeline: one barrier per interval ========
  for (int k = 0; k <= TMAIN + 1; ++k) {
    if (wid < 2) {
      // store out(k-3) (lin partials written by waves45 at interval k-1)
      if (k >= 3 && lane == 63) {
        const int m = k - 3;
        const int sq = wid;
        float o = lds_lin[m & 1][sq][0] + lds_lin[m & 1][sq][1] + blin_s;
        out[(s0 + sq) * TT + m] = o;
      }
      if (k < TMAIN) {
        // h1(k) = cell1(x(k), h1(k-1));  h1(m) lives in buffer (m+1)&1
        float xA = lds_x[0][k], xB = lds_x[1][k];
        float aA[2], aB[2];
#pragma unroll
        for (int g = 0; g < 2; ++g) {
          aA[g] = fmaf(xA, wi1g[g], bias[g]);
          aB[g] = fmaf(xB, wi1g[g], bias[g]);
        }
        dot2x(lds_h1[0][k & 1], lds_h1[1][k & 1], w2, w50, aA, aB);
        float pA0 = __shfl_xor(aA[0], 32), pA1 = __shfl_xor(aA[1], 32);
        float pB0 = __shfl_xor(aB[0], 32), pB1 = __shfl_xor(aB[1], 32);
        float giA = half ? pA0 : aA[0], gfA = half ? pA1 : aA[1];
        float ggA = half ? aA[0] : pA0, goA = half ? aA[1] : pA1;
        float giB = half ? pB0 : aB[0], gfB = half ? pB1 : aB[1];
        float ggB = half ? aB[0] : pB0, goB = half ? aB[1] : pB1;
        cA = fast_sigmoid(gfA) * cA + fast_sigmoid(giA) * fast_tanh(ggA);
        cB = fast_sigmoid(gfB) * cB + fast_sigmoid(giB) * fast_tanh(ggB);
        float hA = fast_sigmoid(goA) * fast_tanh(cA);
        float hB = fast_sigmoid(goB) * fast_tanh(cB);
        if (act && half == 0) {
          lds_h1[0][(k + 1) & 1][u] = hA;
          lds_h1[1][(k + 1) & 1][u] = hB;
        }
      }
    } else if (wid < 4) {
      if (k >= 1 && k <= TMAIN) {
        // pi(k-1) = Wi2 @ h1(k-1) + b2   (h1(k-1) in buffer k&1)
        float aA[2] = {bias[0], bias[1]}, aB[2] = {bias[0], bias[1]};
        dot2x(lds_h1[0][k & 1], lds_h1[1][k & 1], w2, w50, aA, aB);
        if (act) {
          const int pm = (k - 1) & 1;
          lds_pi[pm][0][g0 + 0][u] = aA[0];
          lds_pi[pm][0][g0 + 1][u] = aA[1];
          lds_pi[pm][1][g0 + 0][u] = aB[0];
          lds_pi[pm][1][g0 + 1][u] = aB[1];
        }
      }
    } else {
      if (k >= 2) {
        // h2(m) = cell2(pi(m) + Wh2 @ h2(m-1)), m = k-2; lin partial
        const int m = k - 2;
        float aA[2], aB[2];
        aA[0] = lds_pi[m & 1][0][g0 + 0][u];
        aA[1] = lds_pi[m & 1][0][g0 + 1][u];
        aB[0] = lds_pi[m & 1][1][g0 + 0][u];
        aB[1] = lds_pi[m & 1][1][g0 + 1][u];
        dot2x(lds_h2[0][(m - 1) & 1], lds_h2[1][(m - 1) & 1], w2, w50, aA, aB);
        float pA0 = __shfl_xor(aA[0], 32), pA1 = __shfl_xor(aA[1], 32);
        float pB0 = __shfl_xor(aB[0], 32), pB1 = __shfl_xor(aB[1], 32);
        float giA = half ? pA0 : aA[0], gfA = half ? pA1 : aA[1];
        float ggA = half ? aA[0] : pA0, goA = half ? aA[1] : pA1;
        float giB = half ? pB0 : aB[0], gfB = half ? pB1 : aB[1];
        float ggB = half ? aB[0] : pB0, goB = half ? aB[1] : pB1;
        cA = fast_sigmoid(gfA) * cA + fast_sigmoid(giA) * fast_tanh(ggA);
        cB = fast_sigmoid(gfB) * cB + fast_sigmoid(giB) * fast_tanh(ggB);
        float hA = fast_sigmoid(goA) * fast_tanh(cA);
        float hB = fast_sigmoid(goB) * fast_tanh(cB);
        float val = 0.0f;
        if (act) {
          if (half == 0) {
            lds_h2[0][m & 1][u] = hA;
            val = wlin_u * hA;
          } else {
            lds_h2[1][m & 1][u] = hB;
            val = wlin_u * hB;
          }
        }
#pragma unroll
        for (int off = 16; off >= 1; off >>= 1) val += __shfl_xor(val, off);
        if (lane == 0) lds_lin[m & 1][0][wid - 4] = val;
        if (lane == 32) lds_lin[m & 1][1][wid - 4] = val;
      }
    }
    __syncthreads();
  }

  // =============== feedback phase: 3 sub-phases, serial ================
  for (int t = TMAIN; t < TT; ++t) {
    float phA[2] = {0.f, 0.f}, phB[2] = {0.f, 0.f};
    // --- A: L1 cell with feedback x; waves45 pre-dot Wh2 @ h2(t-1) ---
    if (wid < 2) {
      float oA = lds_lin[(t - 1) & 1][0][0] + lds_lin[(t - 1) & 1][0][1] +
                 blin_s;
      float oB = lds_lin[(t - 1) & 1][1][0] + lds_lin[(t - 1) & 1][1][1] +
                 blin_s;
      if (lane == 63) {
        if (wid == 0) out[s0 * TT + (t - 1)] = oA;
        else          out[(s0 + 1) * TT + (t - 1)] = oB;
      }
      float aA[2], aB[2];
#pragma unroll
      for (int g = 0; g < 2; ++g) {
        aA[g] = fmaf(oA, wi1g[g], bias[g]);
        aB[g] = fmaf(oB, wi1g[g], bias[g]);
      }
      dot2x(lds_h1[0][t & 1], lds_h1[1][t & 1], w2, w50, aA, aB);
      float pA0 = __shfl_xor(aA[0], 32), pA1 = __shfl_xor(aA[1], 32);
      float pB0 = __shfl_xor(aB[0], 32), pB1 = __shfl_xor(aB[1], 32);
      float giA = half ? pA0 : aA[0], gfA = half ? pA1 : aA[1];
      float ggA = half ? aA[0] : pA0, goA = half ? aA[1] : pA1;
      float giB = half ? pB0 : aB[0], gfB = half ? pB1 : aB[1];
      float ggB = half ? aB[0] : pB0, goB = half ? aB[1] : pB1;
      cA = fast_sigmoid(gfA) * cA + fast_sigmoid(giA) * fast_tanh(ggA);
      cB = fast_sigmoid(gfB) * cB + fast_sigmoid(giB) * fast_tanh(ggB);
      float hA = fast_sigmoid(goA) * fast_tanh(cA);
      float hB = fast_sigmoid(goB) * fast_tanh(cB);
      if (act && half == 0) {
        lds_h1[0][(t + 1) & 1][u] = hA;
        lds_h1[1][(t + 1) & 1][u] = hB;
      }
    } else if (wid >= 4) {
      dot2x(lds_h2[0][(t - 1) & 1], lds_h2[1][(t - 1) & 1], w2, w50, phA, phB);
    }
    __syncthreads();
    // --- B: pi(t) = Wi2 @ h1(t) + b2 ---
    if (wid >= 2 && wid < 4) {
      float aA[2] = {bias[0], bias[1]}, aB[2] = {bias[0], bias[1]};
      dot2x(lds_h1[0][(t + 1) & 1], lds_h1[1][(t + 1) & 1], w2, w50, aA, aB);
      if (act) {
        const int pm = t & 1;
        lds_pi[pm][0][g0 + 0][u] = aA[0];
        lds_pi[pm][0][g0 + 1][u] = aA[1];
        lds_pi[pm][1][g0 + 0][u] = aB[0];
        lds_pi[pm][1][g0 + 1][u] = aB[1];
      }
    }
    __syncthreads();
    // --- C: L2 cell + linear head ---
    if (wid >= 4) {
      float aA[2], aB[2];
      aA[0] = lds_pi[t & 1][0][g0 + 0][u] + phA[0];
      aA[1] = lds_pi[t & 1][0][g0 + 1][u] + phA[1];
      aB[0] = lds_pi[t & 1][1][g0 + 0][u] + phB[0];
      aB[1] = lds_pi[t & 1][1][g0 + 1][u] + phB[1];
      float pA0 = __shfl_xor(aA[0], 32), pA1 = __shfl_xor(aA[1], 32);
      float pB0 = __shfl_xor(aB[0], 32), pB1 = __shfl_xor(aB[1], 32);
      float giA = half ? pA0 : aA[0], gfA = half ? pA1 : aA[1];
      float ggA = half ? aA[0] : pA0, goA = half ? aA[1] : pA1;
      float giB = half ? pB0 : aB[0], gfB = half ? pB1 : aB[1];
      float ggB = half ? aB[0] : pB0, goB = half ? aB[1] : pB1;
      cA = fast_sigmoid(gfA) * cA + fast_sigmoid(giA) * fast_tanh(ggA);
      cB = fast_sigmoid(gfB) * cB + fast_sigmoid(giB) * fast_tanh(ggB);
      float hA = fast_sigmoid(goA) * fast_tanh(cA);
      float hB = fast_sigmoid(goB) * fast_tanh(cB);
      float val = 0.0f;
      if (act) {
        if (half == 0) {
          lds_h2[0][t & 1][u] = hA;
          val = wlin_u * hA;
        } else {
          lds_h2[1][t & 1][u] = hB;
          val = wlin_u * hB;
        }
      }
#pragma unroll
      for (int off = 16; off >= 1; off >>= 1) val += __shfl_xor(val, off);
      if (lane == 0) lds_lin[t & 1][0][wid - 4] = val;
      if (lane == 32) lds_lin[t & 1][1][wid - 4] = val;
    }
    __syncthreads();
  }

  // epilogue: store out(TT-1)
  if (wid < 2 && lane == 63) {
    const int sq = wid;
    float o = lds_lin[(TT - 1) & 1][sq][0] + lds_lin[(TT - 1) & 1][sq][1] +
              blin_s;
    out[(s0 + sq) * TT + (TT - 1)] = o;
  }
}

extern "C" void kernel_launch(void* const* d_in, const int* in_sizes, int n_in,
                              void* d_out, int out_size, void* d_ws,
                              size_t ws_size, hipStream_t stream) {
  const float* input = (const float*)d_in[0];
  const float* Wi1 = (const float*)d_in[1];
  const float* Wh1 = (const float*)d_in[2];
  const float* bi1 = (const float*)d_in[3];
  const float* bh1 = (const float*)d_in[4];
  const float* Wi2 = (const float*)d_in[5];
  const float* Wh2 = (const float*)d_in[6];
  const float* bi2 = (const float*)d_in[7];
  const float* bh2 = (const float*)d_in[8];
  const float* Wlin = (const float*)d_in[9];
  const float* blin = (const float*)d_in[10];
  float* out = (float*)d_out;

  const int B = in_sizes[0] / TMAIN;  // 512
  lstm2_persistent<<<B / 2, 384, 0, stream>>>(input, Wi1, Wh1, bi1, bh1, Wi2,
                                              Wh2, bi2, bh2, Wlin, blin, out);
}

// Round 8
// 1511.114 us; speedup vs baseline: 9.7893x; 1.1796x over previous
//
#include <hip/hip_runtime.h>
#include <math.h>

#define HID 51
#define TMAIN 1024
#define FUT 64
#define TT (TMAIN + FUT)

typedef float v2f __attribute__((ext_vector_type(2)));

__device__ __forceinline__ float fast_sigmoid(float x) {
  return 1.0f / (1.0f + __expf(-x));
}
__device__ __forceinline__ float fast_tanh(float x) {
  // stable both directions: x>>0 -> 1, x<<0 -> -1
  return 1.0f - 2.0f / (__expf(2.0f * x) + 1.0f);
}

// Dual-sequence packed dot: acc{A,B}[g] += sum_k w[g][k] * h{A,B}[k].
// K consumed as float2 pairs -> v_pk_fma_f32. h read as float4; a4[12]
// reads h[48..51], in-bounds of the [64] buffers (h[51] junk unused).
__device__ __forceinline__ void dot2x(const float* hA, const float* hB,
                                      const v2f (&w2)[2][25],
                                      const float (&w50)[2],
                                      float (&aA)[2], float (&aB)[2]) {
  const float4* a4 = reinterpret_cast<const float4*>(hA);
  const float4* b4 = reinterpret_cast<const float4*>(hB);
  v2f sA0 = {0.f, 0.f}, sA1 = {0.f, 0.f};
  v2f sB0 = {0.f, 0.f}, sB1 = {0.f, 0.f};
#pragma unroll
  for (int q = 0; q < 12; ++q) {
    float4 av = a4[q];
    float4 bv = b4[q];
    v2f alo = {av.x, av.y}, ahi = {av.z, av.w};
    v2f blo = {bv.x, bv.y}, bhi = {bv.z, bv.w};
    sA0 = __builtin_elementwise_fma(alo, w2[0][2 * q + 0], sA0);
    sB0 = __builtin_elementwise_fma(blo, w2[0][2 * q + 0], sB0);
    sA1 = __builtin_elementwise_fma(alo, w2[1][2 * q + 0], sA1);
    sB1 = __builtin_elementwise_fma(blo, w2[1][2 * q + 0], sB1);
    sA0 = __builtin_elementwise_fma(ahi, w2[0][2 * q + 1], sA0);
    sB0 = __builtin_elementwise_fma(bhi, w2[0][2 * q + 1], sB0);
    sA1 = __builtin_elementwise_fma(ahi, w2[1][2 * q + 1], sA1);
    sB1 = __builtin_elementwise_fma(bhi, w2[1][2 * q + 1], sB1);
  }
  float4 at = a4[12];
  float4 bt = b4[12];
  v2f alo = {at.x, at.y}, blo = {bt.x, bt.y};
  sA0 = __builtin_elementwise_fma(alo, w2[0][24], sA0);
  sB0 = __builtin_elementwise_fma(blo, w2[0][24], sB0);
  sA1 = __builtin_elementwise_fma(alo, w2[1][24], sA1);
  sB1 = __builtin_elementwise_fma(blo, w2[1][24], sB1);
  aA[0] = fmaf(at.z, w50[0], aA[0] + sA0.x + sA0.y);
  aB[0] = fmaf(bt.z, w50[0], aB[0] + sB0.x + sB0.y);
  aA[1] = fmaf(at.z, w50[1], aA[1] + sA1.x + sA1.y);
  aB[1] = fmaf(bt.z, w50[1], aB[1] + sB1.x + sB1.y);
}

// One block = TWO sequences, 6 waves, software-pipelined (R6 skew):
//   interval k:
//     waves 0,1 (Wh1+b1): h1(k)   = cell1(x(k), h1(k-1))
//     waves 2,3 (Wi2+b2): pi(k-1) = Wi2 @ h1(k-1) + b2
//                         + DEFERRED linear head: out(k-3) = wlin.h2(k-3)
//                           (wave2 = seqA, wave3 = seqB; butterfly overlaps
//                            their dot; h2(k-3) parity-safe until k+1)
//     waves 4,5 (Wh2):    h2(k-2) = cell2(pi(k-2) + Wh2 @ h2(k-3))
// R7 lesson: issue count is NOT the limiter (pk_fma halved insts, -2.4%);
// the pacing chain was waves45's 5-deep ds_swizzle butterfly + the
// every-interval global out-store draining vmcnt at __syncthreads.
// This round: butterfly moved to waves23 (overlapped), outputs batched in
// an LDS ring and flushed 64-at-a-time (coalesced, amortized drain).
__global__ __launch_bounds__(384, 2)
void lstm2_persistent(const float* __restrict__ input,
                      const float* __restrict__ Wi1,
                      const float* __restrict__ Wh1,
                      const float* __restrict__ bi1,
                      const float* __restrict__ bh1,
                      const float* __restrict__ Wi2,
                      const float* __restrict__ Wh2,
                      const float* __restrict__ bi2,
                      const float* __restrict__ bh2,
                      const float* __restrict__ Wlin,
                      const float* __restrict__ blin,
                      float* __restrict__ out) {
  __shared__ __align__(16) float lds_x[2][TMAIN];       // [seq][t]
  __shared__ __align__(16) float lds_h1[2][2][64];      // [seq][parity][unit]
  __shared__ __align__(16) float lds_h2[2][2][64];      // [seq][parity][unit]
  __shared__ __align__(16) float lds_pi[2][2][4][64];   // [parity][seq][gate][u]
  __shared__ __align__(16) float lds_outbuf[2][128];    // [seq][slot] out ring
  __shared__ float lds_lin[2][2][2];                    // [parity][seq][wavehalf]

  const int tid = threadIdx.x;
  const int s0 = blockIdx.x * 2;  // sequence pair
  const int wid = tid >> 6;       // 0..5
  const int lane = tid & 63;
  const int half = lane >> 5;   // 0: gates {i,f}, 1: gates {g,o}
  const int l5 = lane & 31;
  const int base = (wid & 1) * 26;
  const int nu = (wid & 1) ? 25 : 26;
  const bool act = l5 < nu;
  const int u = base + (act ? l5 : 0);  // clamped unit index
  const int g0 = half * 2;
  const int seq23 = (wid == 3) ? 1 : 0;  // lin-head seq for waves 2/3

  // Stage both sequences' inputs into LDS (coalesced).
  for (int i = tid; i < TMAIN; i += 384) {
    lds_x[0][i] = input[s0 * TMAIN + i];
    lds_x[1][i] = input[(s0 + 1) * TMAIN + i];
  }
  if (tid < 64) {
#pragma unroll
    for (int p = 0; p < 2; ++p) {
      lds_h1[0][p][tid] = 0.0f;
      lds_h1[1][p][tid] = 0.0f;
      lds_h2[0][p][tid] = 0.0f;
      lds_h2[1][p][tid] = 0.0f;
    }
  }

  // ---- Load this lane's 2 weight rows (shared by both sequences) ----
  v2f w2[2][25];    // k=0..49 as pairs
  float w50[2];     // k=50
  float bias[2] = {0.f, 0.f};
  float wi1g[2] = {0.f, 0.f};
  float wlin_u = 0.0f;     // waves 4,5: feedback-phase butterfly weight
  float wlin_lane = 0.0f;  // waves 2,3: main-phase lin head (lane = unit)
  float cA = 0.0f, cB = 0.0f;  // cell states (L1 waves01, L2 waves45)

  const float* Wsel = (wid < 2) ? Wh1 : ((wid < 4) ? Wi2 : Wh2);
#pragma unroll
  for (int g = 0; g < 2; ++g) {
    const float* row = Wsel + ((g0 + g) * HID + u) * HID;
#pragma unroll
    for (int p = 0; p < 25; ++p) {
      v2f t;
      t.x = row[2 * p + 0];
      t.y = row[2 * p + 1];
      w2[g][p] = t;
    }
    w50[g] = row[50];
  }
  if (wid < 2) {
#pragma unroll
    for (int g = 0; g < 2; ++g) {
      bias[g] = bi1[(g0 + g) * HID + u] + bh1[(g0 + g) * HID + u];
      wi1g[g] = Wi1[(g0 + g) * HID + u];
    }
  } else if (wid < 4) {
#pragma unroll
    for (int g = 0; g < 2; ++g)
      bias[g] = bi2[(g0 + g) * HID + u] + bh2[(g0 + g) * HID + u];
    wlin_lane = (lane < HID) ? Wlin[lane] : 0.0f;
  } else {
    wlin_u = Wlin[u];
  }
  const float blin_s = blin[0];

  // ---- PIN: opaque asm defs prevent remat of the invariant weight loads.
#pragma unroll
  for (int g = 0; g < 2; ++g) {
#pragma unroll
    for (int p = 0; p < 25; ++p) asm volatile("" : "+v"(w2[g][p]));
    asm volatile("" : "+v"(w50[g]), "+v"(bias[g]), "+v"(wi1g[g]));
  }
  asm volatile("" : "+v"(wlin_u), "+v"(wlin_lane));

  __syncthreads();

  // =============== main-phase pipeline: one barrier per interval ========
  // k = 0..TMAIN+2; lin head lags 3 intervals (m = k-3 <= 1023).
  for (int k = 0; k <= TMAIN + 2; ++k) {
    if (wid < 2) {
      if (k < TMAIN) {
        // h1(k) = cell1(x(k), h1(k-1));  h1(m) lives in buffer (m+1)&1
        float xA = lds_x[0][k], xB = lds_x[1][k];
        float aA[2], aB[2];
#pragma unroll
        for (int g = 0; g < 2; ++g) {
          aA[g] = fmaf(xA, wi1g[g], bias[g]);
          aB[g] = fmaf(xB, wi1g[g], bias[g]);
        }
        dot2x(lds_h1[0][k & 1], lds_h1[1][k & 1], w2, w50, aA, aB);
        float pA0 = __shfl_xor(aA[0], 32), pA1 = __shfl_xor(aA[1], 32);
        float pB0 = __shfl_xor(aB[0], 32), pB1 = __shfl_xor(aB[1], 32);
        float giA = half ? pA0 : aA[0], gfA = half ? pA1 : aA[1];
        float ggA = half ? aA[0] : pA0, goA = half ? aA[1] : pA1;
        float giB = half ? pB0 : aB[0], gfB = half ? pB1 : aB[1];
        float ggB = half ? aB[0] : pB0, goB = half ? aB[1] : pB1;
        cA = fast_sigmoid(gfA) * cA + fast_sigmoid(giA) * fast_tanh(ggA);
        cB = fast_sigmoid(gfB) * cB + fast_sigmoid(giB) * fast_tanh(ggB);
        float hA = fast_sigmoid(goA) * fast_tanh(cA);
        float hB = fast_sigmoid(goB) * fast_tanh(cB);
        if (act && half == 0) {
          lds_h1[0][(k + 1) & 1][u] = hA;
          lds_h1[1][(k + 1) & 1][u] = hB;
        }
      }
    } else if (wid < 4) {
      if (k >= 1 && k <= TMAIN) {
        // pi(k-1) = Wi2 @ h1(k-1) + b2   (h1(k-1) in buffer k&1)
        float aA[2] = {bias[0], bias[1]}, aB[2] = {bias[0], bias[1]};
        dot2x(lds_h1[0][k & 1], lds_h1[1][k & 1], w2, w50, aA, aB);
        if (act) {
          const int pm = (k - 1) & 1;
          lds_pi[pm][0][g0 + 0][u] = aA[0];
          lds_pi[pm][0][g0 + 1][u] = aA[1];
          lds_pi[pm][1][g0 + 0][u] = aB[0];
          lds_pi[pm][1][g0 + 1][u] = aB[1];
        }
      }
      if (k >= 3) {
        // deferred lin head: out(m) = wlin . h2(m) + blin, m = k-3.
        // h2(m) in buffer m&1 (written interval m+2 = k-1; overwritten at
        // k+1) -> safe. Lanes 51..63 read zero-initialized entries.
        const int m = k - 3;
        float hv = lds_h2[seq23][m & 1][lane];
        float val = wlin_lane * hv;
#pragma unroll
        for (int off = 32; off >= 1; off >>= 1) val += __shfl_xor(val, off);
        if (lane == 0) lds_outbuf[seq23][m & 127] = val + blin_s;
        if ((m & 63) == 63) {
          // flush 64 finished outputs, coalesced (same-wave LDS order OK)
          const int idx = (m - 63) + lane;
          out[(s0 + seq23) * TT + idx] = lds_outbuf[seq23][idx & 127];
        }
      }
    } else {
      if (k >= 2 && k <= TMAIN + 1) {
        // h2(m2) = cell2(pi(m2) + Wh2 @ h2(m2-1)), m2 = k-2
        const int m2 = k - 2;
        float aA[2], aB[2];
        aA[0] = lds_pi[m2 & 1][0][g0 + 0][u];
        aA[1] = lds_pi[m2 & 1][0][g0 + 1][u];
        aB[0] = lds_pi[m2 & 1][1][g0 + 0][u];
        aB[1] = lds_pi[m2 & 1][1][g0 + 1][u];
        dot2x(lds_h2[0][(m2 - 1) & 1], lds_h2[1][(m2 - 1) & 1], w2, w50, aA,
              aB);
        float pA0 = __shfl_xor(aA[0], 32), pA1 = __shfl_xor(aA[1], 32);
        float pB0 = __shfl_xor(aB[0], 32), pB1 = __shfl_xor(aB[1], 32);
        float giA = half ? pA0 : aA[0], gfA = half ? pA1 : aA[1];
        float ggA = half ? aA[0] : pA0, goA = half ? aA[1] : pA1;
        float giB = half ? pB0 : aB[0], gfB = half ? pB1 : aB[1];
        float ggB = half ? aB[0] : pB0, goB = half ? aB[1] : pB1;
        cA = fast_sigmoid(gfA) * cA + fast_sigmoid(giA) * fast_tanh(ggA);
        cB = fast_sigmoid(gfB) * cB + fast_sigmoid(giB) * fast_tanh(ggB);
        float hA = fast_sigmoid(goA) * fast_tanh(cA);
        float hB = fast_sigmoid(goB) * fast_tanh(cB);
        if (act && half == 0) {
          lds_h2[0][m2 & 1][u] = hA;
          lds_h2[1][m2 & 1][u] = hB;
        }
      }
    }
    __syncthreads();
  }

  // =============== feedback phase: 3 sub-phases, serial ================
  for (int t = TMAIN; t < TT; ++t) {
    float phA[2] = {0.f, 0.f}, phB[2] = {0.f, 0.f};
    // --- A: L1 cell with feedback x; waves45 pre-dot Wh2 @ h2(t-1) ---
    if (wid < 2) {
      float oA, oB;
      if (t == TMAIN) {
        oA = lds_outbuf[0][127];  // out(1023), written at main k=1026
        oB = lds_outbuf[1][127];
      } else {
        oA = lds_lin[(t - 1) & 1][0][0] + lds_lin[(t - 1) & 1][0][1] + blin_s;
        oB = lds_lin[(t - 1) & 1][1][0] + lds_lin[(t - 1) & 1][1][1] + blin_s;
        if (lane == 0) {  // buffer future outputs; flushed in epilogue
          if (wid == 0) lds_outbuf[0][(t - 1) & 127] = oA;
          else          lds_outbuf[1][(t - 1) & 127] = oB;
        }
      }
      float aA[2], aB[2];
#pragma unroll
      for (int g = 0; g < 2; ++g) {
        aA[g] = fmaf(oA, wi1g[g], bias[g]);
        aB[g] = fmaf(oB, wi1g[g], bias[g]);
      }
      dot2x(lds_h1[0][t & 1], lds_h1[1][t & 1], w2, w50, aA, aB);
      float pA0 = __shfl_xor(aA[0], 32), pA1 = __shfl_xor(aA[1], 32);
      float pB0 = __shfl_xor(aB[0], 32), pB1 = __shfl_xor(aB[1], 32);
      float giA = half ? pA0 : aA[0], gfA = half ? pA1 : aA[1];
      float ggA = half ? aA[0] : pA0, goA = half ? aA[1] : pA1;
      float giB = half ? pB0 : aB[0], gfB = half ? pB1 : aB[1];
      float ggB = half ? aB[0] : pB0, goB = half ? aB[1] : pB1;
      cA = fast_sigmoid(gfA) * cA + fast_sigmoid(giA) * fast_tanh(ggA);
      cB = fast_sigmoid(gfB) * cB + fast_sigmoid(giB) * fast_tanh(ggB);
      float hA = fast_sigmoid(goA) * fast_tanh(cA);
      float hB = fast_sigmoid(goB) * fast_tanh(cB);
      if (act && half == 0) {
        lds_h1[0][(t + 1) & 1][u] = hA;
        lds_h1[1][(t + 1) & 1][u] = hB;
      }
    } else if (wid >= 4) {
      dot2x(lds_h2[0][(t - 1) & 1], lds_h2[1][(t - 1) & 1], w2, w50, phA, phB);
    }
    __syncthreads();
    // --- B: pi(t) = Wi2 @ h1(t) + b2 ---
    if (wid >= 2 && wid < 4) {
      float aA[2] = {bias[0], bias[1]}, aB[2] = {bias[0], bias[1]};
      dot2x(lds_h1[0][(t + 1) & 1], lds_h1[1][(t + 1) & 1], w2, w50, aA, aB);
      if (act) {
        const int pm = t & 1;
        lds_pi[pm][0][g0 + 0][u] = aA[0];
        lds_pi[pm][0][g0 + 1][u] = aA[1];
        lds_pi[pm][1][g0 + 0][u] = aB[0];
        lds_pi[pm][1][g0 + 1][u] = aB[1];
      }
    }
    __syncthreads();
    // --- C: L2 cell + linear head (butterfly stays here in feedback) ---
    if (wid >= 4) {
      float aA[2], aB[2];
      aA[0] = lds_pi[t & 1][0][g0 + 0][u] + phA[0];
      aA[1] = lds_pi[t & 1][0][g0 + 1][u] + phA[1];
      aB[0] = lds_pi[t & 1][1][g0 + 0][u] + phB[0];
      aB[1] = lds_pi[t & 1][1][g0 + 1][u] + phB[1];
      float pA0 = __shfl_xor(aA[0], 32), pA1 = __shfl_xor(aA[1], 32);
      float pB0 = __shfl_xor(aB[0], 32), pB1 = __shfl_xor(aB[1], 32);
      float giA = half ? pA0 : aA[0], gfA = half ? pA1 : aA[1];
      float ggA = half ? aA[0] : pA0, goA = half ? aA[1] : pA1;
      float giB = half ? pB0 : aB[0], gfB = half ? pB1 : aB[1];
      float ggB = half ? aB[0] : pB0, goB = half ? aB[1] : pB1;
      cA = fast_sigmoid(gfA) * cA + fast_sigmoid(giA) * fast_tanh(ggA);
      cB = fast_sigmoid(gfB) * cB + fast_sigmoid(giB) * fast_tanh(ggB);
      float hA = fast_sigmoid(goA) * fast_tanh(cA);
      float hB = fast_sigmoid(goB) * fast_tanh(cB);
      float val = 0.0f;
      if (act) {
        if (half == 0) {
          lds_h2[0][t & 1][u] = hA;
          val = wlin_u * hA;
        } else {
          lds_h2[1][t & 1][u] = hB;
          val = wlin_u * hB;
        }
      }
#pragma unroll
      for (int off = 16; off >= 1; off >>= 1) val += __shfl_xor(val, off);
      if (lane == 0) lds_lin[t & 1][0][wid - 4] = val;
      if (lane == 32) lds_lin[t & 1][1][wid - 4] = val;
    }
    __syncthreads();
  }

  // epilogue: buffer out(TT-1), then flush the 64 future outputs
  if (wid < 2 && lane == 0) {
    float o = lds_lin[(TT - 1) & 1][wid][0] + lds_lin[(TT - 1) & 1][wid][1] +
              blin_s;
    lds_outbuf[wid][(TT - 1) & 127] = o;  // slot 63
  }
  __syncthreads();
  if (wid >= 2 && wid < 4) {
    const int tt = TMAIN + lane;  // 1024..1087 -> slots 0..63
    out[(s0 + seq23) * TT + tt] = lds_outbuf[seq23][tt & 127];
  }
}

extern "C" void kernel_launch(void* const* d_in, const int* in_sizes, int n_in,
                              void* d_out, int out_size, void* d_ws,
                              size_t ws_size, hipStream_t stream) {
  const float* input = (const float*)d_in[0];
  const float* Wi1 = (const float*)d_in[1];
  const float* Wh1 = (const float*)d_in[2];
  const float* bi1 = (const float*)d_in[3];
  const float* bh1 = (const float*)d_in[4];
  const float* Wi2 = (const float*)d_in[5];
  const float* Wh2 = (const float*)d_in[6];
  const float* bi2 = (const float*)d_in[7];
  const float* bh2 = (const float*)d_in[8];
  const float* Wlin = (const float*)d_in[9];
  const float* blin = (const float*)d_in[10];
  float* out = (float*)d_out;

  const int B = in_sizes[0] / TMAIN;  // 512
  lstm2_persistent<<<B / 2, 384, 0, stream>>>(input, Wi1, Wh1, bi1, bh1, Wi2,
                                              Wh2, bi2, bh2, Wlin, blin, out);
}

// Round 9
// 1393.516 us; speedup vs baseline: 10.6154x; 1.0844x over previous
//
#include <hip/hip_runtime.h>
#include <math.h>

#define HID 51
#define TMAIN 1024
#define FUT 64
#define TT (TMAIN + FUT)
#define RING 128   // h2 history ring depth (pow2)
#define RPAD 68    // ring row stride in floats: 16B-aligned (68*4=272), bank-skewed

typedef float v2f __attribute__((ext_vector_type(2)));

__device__ __forceinline__ float fast_sigmoid(float x) {
  return 1.0f / (1.0f + __expf(-x));
}
__device__ __forceinline__ float fast_tanh(float x) {
  // stable both directions: x>>0 -> 1, x<<0 -> -1
  return 1.0f - 2.0f / (__expf(2.0f * x) + 1.0f);
}

// Dual-sequence packed full-K dot: acc{A,B}[g] += sum_k w[g][k]*h{A,B}[k].
// float4 LDS reads; a4[12] touches h[48..51] (element 51 loaded but unused).
__device__ __forceinline__ void dot2x(const float* hA, const float* hB,
                                      const v2f (&w2)[2][25],
                                      const float (&w50)[2],
                                      float (&aA)[2], float (&aB)[2]) {
  const float4* a4 = reinterpret_cast<const float4*>(hA);
  const float4* b4 = reinterpret_cast<const float4*>(hB);
  v2f sA0 = {0.f, 0.f}, sA1 = {0.f, 0.f};
  v2f sB0 = {0.f, 0.f}, sB1 = {0.f, 0.f};
#pragma unroll
  for (int q = 0; q < 12; ++q) {
    float4 av = a4[q];
    float4 bv = b4[q];
    v2f alo = {av.x, av.y}, ahi = {av.z, av.w};
    v2f blo = {bv.x, bv.y}, bhi = {bv.z, bv.w};
    sA0 = __builtin_elementwise_fma(alo, w2[0][2 * q + 0], sA0);
    sB0 = __builtin_elementwise_fma(blo, w2[0][2 * q + 0], sB0);
    sA1 = __builtin_elementwise_fma(alo, w2[1][2 * q + 0], sA1);
    sB1 = __builtin_elementwise_fma(blo, w2[1][2 * q + 0], sB1);
    sA0 = __builtin_elementwise_fma(ahi, w2[0][2 * q + 1], sA0);
    sB0 = __builtin_elementwise_fma(bhi, w2[0][2 * q + 1], sB0);
    sA1 = __builtin_elementwise_fma(ahi, w2[1][2 * q + 1], sA1);
    sB1 = __builtin_elementwise_fma(bhi, w2[1][2 * q + 1], sB1);
  }
  float4 at = a4[12];
  float4 bt = b4[12];
  v2f alo = {at.x, at.y}, blo = {bt.x, bt.y};
  sA0 = __builtin_elementwise_fma(alo, w2[0][24], sA0);
  sB0 = __builtin_elementwise_fma(blo, w2[0][24], sB0);
  sA1 = __builtin_elementwise_fma(alo, w2[1][24], sA1);
  sB1 = __builtin_elementwise_fma(blo, w2[1][24], sB1);
  aA[0] = fmaf(at.z, w50[0], aA[0] + sA0.x + sA0.y);
  aB[0] = fmaf(bt.z, w50[0], aB[0] + sB0.x + sB0.y);
  aA[1] = fmaf(at.z, w50[1], aA[1] + sA1.x + sA1.y);
  aB[1] = fmaf(bt.z, w50[1], aB[1] + sB1.x + sB1.y);
}

// Half-K dual-seq dot: 13 float2 pairs starting at a pre-offset pointer.
// K2 waves' pair 12 multiplies {h[50],h[51]} by {w50,0}; h1[51] is kept 0.
__device__ __forceinline__ void dotH(const float* hA, const float* hB,
                                     const v2f (&w)[2][13],
                                     float (&aA)[2], float (&aB)[2]) {
  const float2* a2 = reinterpret_cast<const float2*>(hA);
  const float2* b2 = reinterpret_cast<const float2*>(hB);
  v2f sA0 = {0.f, 0.f}, sA1 = {0.f, 0.f};
  v2f sB0 = {0.f, 0.f}, sB1 = {0.f, 0.f};
#pragma unroll
  for (int p = 0; p < 13; ++p) {
    float2 av = a2[p], bv = b2[p];
    v2f a = {av.x, av.y}, b = {bv.x, bv.y};
    sA0 = __builtin_elementwise_fma(a, w[0][p], sA0);
    sB0 = __builtin_elementwise_fma(b, w[0][p], sB0);
    sA1 = __builtin_elementwise_fma(a, w[1][p], sA1);
    sB1 = __builtin_elementwise_fma(b, w[1][p], sB1);
  }
  aA[0] = sA0.x + sA0.y;
  aB[0] = sB0.x + sB0.y;
  aA[1] = sA1.x + sA1.y;
  aB[1] = sB1.x + sB1.y;
}

// One block = TWO sequences, 8 waves. R8 lesson: the pacing SIMDs hosted
// TWO heavy cell waves each ({L1, Wh2-cell} round-robin pairing) while
// Wi2 waves idled their SIMDs -> interval set by ~1800cy of issue on the
// loaded SIMDs. This round balances: Wi2 is split into 4 half-K waves so
// round-robin pairs every SIMD as {cell wave + light half-K wave}:
//   wid0,1: L1 cell, units [0,26)/[26,51)
//   wid2,3: Wh2 cell (L2), units [0,26)/[26,51)   [carry c2; feedback lin]
//   wid4,5: Wi2 K[26,51) partial -> piK2           [+ main-phase out flush]
//   wid6,7: Wi2 K[0,26)  partial -> piK1
// Pipeline skew (1 barrier/interval): h1(k) | piK(k-1) | h2(k-2).
// Linear head is OUT of the loop: h2 history in a 128-ring; every 64
// intervals waves 4,5 compute+store 64 outputs each (plain 51-FMA dots).
// Feedback phase (out->x serial) keeps the 3-sub-phase schedule.
__global__ __launch_bounds__(512, 2)
void lstm2_persistent(const float* __restrict__ input,
                      const float* __restrict__ Wi1,
                      const float* __restrict__ Wh1,
                      const float* __restrict__ bi1,
                      const float* __restrict__ bh1,
                      const float* __restrict__ Wi2,
                      const float* __restrict__ Wh2,
                      const float* __restrict__ bi2,
                      const float* __restrict__ bh2,
                      const float* __restrict__ Wlin,
                      const float* __restrict__ blin,
                      float* __restrict__ out) {
  __shared__ __align__(16) float lds_x[2][TMAIN];          // [seq][t]
  __shared__ __align__(16) float lds_h1[2][2][64];         // [seq][parity][u]
  __shared__ __align__(16) float lds_piK1[2][2][4][64];    // [par][seq][g][u]
  __shared__ __align__(16) float lds_piK2[2][2][4][64];    // [par][seq][g][u]
  __shared__ __align__(16) float lds_h2h[2][RING][RPAD];   // h2 history ring
  __shared__ __align__(16) float lds_wlin[64];
  __shared__ __align__(16) float lds_outbuf[2][64];        // feedback outputs
  __shared__ float lds_lin[2][2][2];                       // [par][seq][cellw]
  __shared__ float lds_fb[2];                              // out(1023) seed

  const int tid = threadIdx.x;
  const int s0 = blockIdx.x * 2;  // sequence pair
  const int wid = tid >> 6;       // 0..7
  const int lane = tid & 63;
  const int half = lane >> 5;   // 0: gates {i,f}, 1: gates {g,o}
  const int l5 = lane & 31;
  const int base = (wid & 1) * 26;
  const int nu = (wid & 1) ? 25 : 26;
  const bool act = l5 < nu;
  const int u = base + (act ? l5 : 0);  // clamped unit index
  const int g0 = half * 2;
  const int koff = (wid >= 6) ? 0 : 26;  // Wi2 K-half offset

  // Stage inputs; zero h1 buffers (incl. elem 51..63 -> dotH pair-12 safe)
  // and ring slot RING-1 (h2(-1) = 0); stage wlin.
  for (int i = tid; i < TMAIN; i += 512) {
    lds_x[0][i] = input[s0 * TMAIN + i];
    lds_x[1][i] = input[(s0 + 1) * TMAIN + i];
  }
  if (tid < 64) {
    lds_h1[0][0][tid] = 0.0f;
    lds_h1[0][1][tid] = 0.0f;
    lds_h1[1][0][tid] = 0.0f;
    lds_h1[1][1][tid] = 0.0f;
    lds_wlin[tid] = (tid < HID) ? Wlin[tid] : 0.0f;
  }
  if (tid < 128) lds_h2h[tid >> 6][RING - 1][tid & 63] = 0.0f;

  // ---- weights ----
  v2f w2f[2][25];  // full rows (L1 / Wh2 cell waves)
  float w50f[2] = {0.f, 0.f};
  v2f w2h[2][13];  // half rows (Wi2 waves)
  float bias[2] = {0.f, 0.f};
  float wi1g[2] = {0.f, 0.f};
  float wlin_u = 0.0f;
  float cA = 0.0f, cB = 0.0f;  // cell states (L1 in wid01, L2 in wid23)

  if (wid < 4) {
    const float* Wsel = (wid < 2) ? Wh1 : Wh2;
#pragma unroll
    for (int g = 0; g < 2; ++g) {
      const float* row = Wsel + ((g0 + g) * HID + u) * HID;
#pragma unroll
      for (int p = 0; p < 25; ++p) {
        v2f t;
        t.x = row[2 * p + 0];
        t.y = row[2 * p + 1];
        w2f[g][p] = t;
      }
      w50f[g] = row[50];
    }
    if (wid < 2) {
#pragma unroll
      for (int g = 0; g < 2; ++g) {
        bias[g] = bi1[(g0 + g) * HID + u] + bh1[(g0 + g) * HID + u];
        wi1g[g] = Wi1[(g0 + g) * HID + u];
      }
    } else {
#pragma unroll
      for (int g = 0; g < 2; ++g)
        bias[g] = bi2[(g0 + g) * HID + u] + bh2[(g0 + g) * HID + u];
      wlin_u = Wlin[u];
    }
#pragma unroll
    for (int g = 0; g < 2; ++g) {
#pragma unroll
      for (int p = 0; p < 25; ++p) asm volatile("" : "+v"(w2f[g][p]));
      asm volatile("" : "+v"(w50f[g]), "+v"(bias[g]), "+v"(wi1g[g]));
    }
    asm volatile("" : "+v"(wlin_u));
  } else {
#pragma unroll
    for (int g = 0; g < 2; ++g) {
      const float* row = Wi2 + ((g0 + g) * HID + u) * HID + koff;
      if (koff == 0) {
#pragma unroll
        for (int p = 0; p < 13; ++p) {
          v2f t;
          t.x = row[2 * p + 0];
          t.y = row[2 * p + 1];
          w2h[g][p] = t;
        }
      } else {
#pragma unroll
        for (int p = 0; p < 12; ++p) {
          v2f t;
          t.x = row[2 * p + 0];
          t.y = row[2 * p + 1];
          w2h[g][p] = t;
        }
        v2f t;
        t.x = row[24];  // K=50
        t.y = 0.0f;     // pairs with h1[51] == 0
        w2h[g][12] = t;
      }
    }
#pragma unroll
    for (int g = 0; g < 2; ++g)
#pragma unroll
      for (int p = 0; p < 13; ++p) asm volatile("" : "+v"(w2h[g][p]));
  }
  const float blin_s = blin[0];

  __syncthreads();

  // =============== main-phase pipeline: one barrier per interval ========
  for (int k = 0; k <= TMAIN + 2; ++k) {
    if (wid < 2) {
      if (k < TMAIN) {
        // h1(k) = cell1(x(k), h1(k-1));  h1(m) lives in buffer (m+1)&1
        float xA = lds_x[0][k], xB = lds_x[1][k];
        float aA[2], aB[2];
#pragma unroll
        for (int g = 0; g < 2; ++g) {
          aA[g] = fmaf(xA, wi1g[g], bias[g]);
          aB[g] = fmaf(xB, wi1g[g], bias[g]);
        }
        dot2x(lds_h1[0][k & 1], lds_h1[1][k & 1], w2f, w50f, aA, aB);
        float pA0 = __shfl_xor(aA[0], 32), pA1 = __shfl_xor(aA[1], 32);
        float pB0 = __shfl_xor(aB[0], 32), pB1 = __shfl_xor(aB[1], 32);
        float giA = half ? pA0 : aA[0], gfA = half ? pA1 : aA[1];
        float ggA = half ? aA[0] : pA0, goA = half ? aA[1] : pA1;
        float giB = half ? pB0 : aB[0], gfB = half ? pB1 : aB[1];
        float ggB = half ? aB[0] : pB0, goB = half ? aB[1] : pB1;
        cA = fast_sigmoid(gfA) * cA + fast_sigmoid(giA) * fast_tanh(ggA);
        cB = fast_sigmoid(gfB) * cB + fast_sigmoid(giB) * fast_tanh(ggB);
        float hA = fast_sigmoid(goA) * fast_tanh(cA);
        float hB = fast_sigmoid(goB) * fast_tanh(cB);
        if (act && half == 0) {
          lds_h1[0][(k + 1) & 1][u] = hA;
          lds_h1[1][(k + 1) & 1][u] = hB;
        }
      }
    } else if (wid < 4) {
      if (k >= 2 && k <= TMAIN + 1) {
        // h2(m2) = cell2(bias + piK1(m2)+piK2(m2) + Wh2 @ h2(m2-1))
        const int m2 = k - 2;
        const int pm = m2 & 1;
        float aA[2], aB[2];
        aA[0] = bias[0] + lds_piK1[pm][0][g0 + 0][u] + lds_piK2[pm][0][g0 + 0][u];
        aA[1] = bias[1] + lds_piK1[pm][0][g0 + 1][u] + lds_piK2[pm][0][g0 + 1][u];
        aB[0] = bias[0] + lds_piK1[pm][1][g0 + 0][u] + lds_piK2[pm][1][g0 + 0][u];
        aB[1] = bias[1] + lds_piK1[pm][1][g0 + 1][u] + lds_piK2[pm][1][g0 + 1][u];
        dot2x(&lds_h2h[0][(m2 - 1) & (RING - 1)][0],
              &lds_h2h[1][(m2 - 1) & (RING - 1)][0], w2f, w50f, aA, aB);
        float pA0 = __shfl_xor(aA[0], 32), pA1 = __shfl_xor(aA[1], 32);
        float pB0 = __shfl_xor(aB[0], 32), pB1 = __shfl_xor(aB[1], 32);
        float giA = half ? pA0 : aA[0], gfA = half ? pA1 : aA[1];
        float ggA = half ? aA[0] : pA0, goA = half ? aA[1] : pA1;
        float giB = half ? pB0 : aB[0], gfB = half ? pB1 : aB[1];
        float ggB = half ? aB[0] : pB0, goB = half ? aB[1] : pB1;
        cA = fast_sigmoid(gfA) * cA + fast_sigmoid(giA) * fast_tanh(ggA);
        cB = fast_sigmoid(gfB) * cB + fast_sigmoid(giB) * fast_tanh(ggB);
        float hA = fast_sigmoid(goA) * fast_tanh(cA);
        float hB = fast_sigmoid(goB) * fast_tanh(cB);
        if (act && half == 0) {
          lds_h2h[0][m2 & (RING - 1)][u] = hA;
          lds_h2h[1][m2 & (RING - 1)][u] = hB;
        }
      }
    } else {
      if (k >= 1 && k <= TMAIN) {
        // piK(k-1) partial: Wi2[:, koff:koff+26] @ h1(k-1)[koff:...]
        float aA[2], aB[2];
        dotH(&lds_h1[0][k & 1][koff], &lds_h1[1][k & 1][koff], w2h, aA, aB);
        const int pm = (k - 1) & 1;
        if (act) {
          if (wid >= 6) {
            lds_piK1[pm][0][g0 + 0][u] = aA[0];
            lds_piK1[pm][0][g0 + 1][u] = aA[1];
            lds_piK1[pm][1][g0 + 0][u] = aB[0];
            lds_piK1[pm][1][g0 + 1][u] = aB[1];
          } else {
            lds_piK2[pm][0][g0 + 0][u] = aA[0];
            lds_piK2[pm][0][g0 + 1][u] = aA[1];
            lds_piK2[pm][1][g0 + 0][u] = aB[0];
            lds_piK2[pm][1][g0 + 1][u] = aB[1];
          }
        }
      }
      // Deferred linear head: every 64 intervals, waves 4,5 emit 64 outs
      // each (chunk c=k-66; h2(c+63) landed at interval c+65; writer this
      // interval touches slot (c+64)&127 -- disjoint from read slots).
      if (wid < 6 && k >= 66 && ((k - 66) & 63) == 0) {
        const int c = k - 66;
        const int seq = wid - 4;
        const int m = c + lane;
        const float* r = &lds_h2h[seq][m & (RING - 1)][0];
        float o0 = 0.f, o1 = 0.f;
#pragma unroll
        for (int j = 0; j < 48; j += 2) {
          o0 = fmaf(lds_wlin[j], r[j], o0);
          o1 = fmaf(lds_wlin[j + 1], r[j + 1], o1);
        }
        o0 = fmaf(lds_wlin[48], r[48], o0);
        o1 = fmaf(lds_wlin[49], r[49], o1);
        o0 = fmaf(lds_wlin[50], r[50], o0);
        float o = o0 + o1 + blin_s;
        out[(s0 + seq) * TT + m] = o;
        if (m == TMAIN - 1) lds_fb[seq] = o;  // feedback seed
      }
    }
    __syncthreads();
  }

  // =============== feedback phase: 3 sub-phases, serial ================
  for (int t = TMAIN; t < TT; ++t) {
    float phA[2] = {0.f, 0.f}, phB[2] = {0.f, 0.f};
    // --- A: L1 cell with feedback x; cell waves pre-dot Wh2 @ h2(t-1) ---
    if (wid < 2) {
      float oA, oB;
      if (t == TMAIN) {
        oA = lds_fb[0];
        oB = lds_fb[1];
      } else {
        oA = lds_lin[(t - 1) & 1][0][0] + lds_lin[(t - 1) & 1][0][1] + blin_s;
        oB = lds_lin[(t - 1) & 1][1][0] + lds_lin[(t - 1) & 1][1][1] + blin_s;
        if (lane == 0) {  // buffer future outputs; flushed in epilogue
          if (wid == 0) lds_outbuf[0][t - 1 - TMAIN] = oA;
          else          lds_outbuf[1][t - 1 - TMAIN] = oB;
        }
      }
      float aA[2], aB[2];
#pragma unroll
      for (int g = 0; g < 2; ++g) {
        aA[g] = fmaf(oA, wi1g[g], bias[g]);
        aB[g] = fmaf(oB, wi1g[g], bias[g]);
      }
      dot2x(lds_h1[0][t & 1], lds_h1[1][t & 1], w2f, w50f, aA, aB);
      float pA0 = __shfl_xor(aA[0], 32), pA1 = __shfl_xor(aA[1], 32);
      float pB0 = __shfl_xor(aB[0], 32), pB1 = __shfl_xor(aB[1], 32);
      float giA = half ? pA0 : aA[0], gfA = half ? pA1 : aA[1];
      float ggA = half ? aA[0] : pA0, goA = half ? aA[1] : pA1;
      float giB = half ? pB0 : aB[0], gfB = half ? pB1 : aB[1];
      float ggB = half ? aB[0] : pB0, goB = half ? aB[1] : pB1;
      cA = fast_sigmoid(gfA) * cA + fast_sigmoid(giA) * fast_tanh(ggA);
      cB = fast_sigmoid(gfB) * cB + fast_sigmoid(giB) * fast_tanh(ggB);
      float hA = fast_sigmoid(goA) * fast_tanh(cA);
      float hB = fast_sigmoid(goB) * fast_tanh(cB);
      if (act && half == 0) {
        lds_h1[0][(t + 1) & 1][u] = hA;
        lds_h1[1][(t + 1) & 1][u] = hB;
      }
    } else if (wid < 4) {
      dot2x(&lds_h2h[0][(t - 1) & (RING - 1)][0],
            &lds_h2h[1][(t - 1) & (RING - 1)][0], w2f, w50f, phA, phB);
    }
    __syncthreads();
    // --- B: piK halves from h1(t) ---
    if (wid >= 4) {
      float aA[2], aB[2];
      dotH(&lds_h1[0][(t + 1) & 1][koff], &lds_h1[1][(t + 1) & 1][koff], w2h,
           aA, aB);
      const int pm = t & 1;
      if (act) {
        if (wid >= 6) {
          lds_piK1[pm][0][g0 + 0][u] = aA[0];
          lds_piK1[pm][0][g0 + 1][u] = aA[1];
          lds_piK1[pm][1][g0 + 0][u] = aB[0];
          lds_piK1[pm][1][g0 + 1][u] = aB[1];
        } else {
          lds_piK2[pm][0][g0 + 0][u] = aA[0];
          lds_piK2[pm][0][g0 + 1][u] = aA[1];
          lds_piK2[pm][1][g0 + 0][u] = aB[0];
          lds_piK2[pm][1][g0 + 1][u] = aB[1];
        }
      }
    }
    __syncthreads();
    // --- C: L2 cell + linear head (butterfly on cell waves here) ---
    if (wid >= 2 && wid < 4) {
      const int pm = t & 1;
      float aA[2], aB[2];
      aA[0] = bias[0] + lds_piK1[pm][0][g0 + 0][u] + lds_piK2[pm][0][g0 + 0][u] + phA[0];
      aA[1] = bias[1] + lds_piK1[pm][0][g0 + 1][u] + lds_piK2[pm][0][g0 + 1][u] + phA[1];
      aB[0] = bias[0] + lds_piK1[pm][1][g0 + 0][u] + lds_piK2[pm][1][g0 + 0][u] + phB[0];
      aB[1] = bias[1] + lds_piK1[pm][1][g0 + 1][u] + lds_piK2[pm][1][g0 + 1][u] + phB[1];
      float pA0 = __shfl_xor(aA[0], 32), pA1 = __shfl_xor(aA[1], 32);
      float pB0 = __shfl_xor(aB[0], 32), pB1 = __shfl_xor(aB[1], 32);
      float giA = half ? pA0 : aA[0], gfA = half ? pA1 : aA[1];
      float ggA = half ? aA[0] : pA0, goA = half ? aA[1] : pA1;
      float giB = half ? pB0 : aB[0], gfB = half ? pB1 : aB[1];
      float ggB = half ? aB[0] : pB0, goB = half ? aB[1] : pB1;
      cA = fast_sigmoid(gfA) * cA + fast_sigmoid(giA) * fast_tanh(ggA);
      cB = fast_sigmoid(gfB) * cB + fast_sigmoid(giB) * fast_tanh(ggB);
      float hA = fast_sigmoid(goA) * fast_tanh(cA);
      float hB = fast_sigmoid(goB) * fast_tanh(cB);
      float val = 0.0f;
      if (act) {
        if (half == 0) {
          lds_h2h[0][t & (RING - 1)][u] = hA;
          val = wlin_u * hA;
        } else {
          lds_h2h[1][t & (RING - 1)][u] = hB;
          val = wlin_u * hB;
        }
      }
#pragma unroll
      for (int off = 16; off >= 1; off >>= 1) val += __shfl_xor(val, off);
      if (lane == 0) lds_lin[t & 1][0][wid - 2] = val;
      if (lane == 32) lds_lin[t & 1][1][wid - 2] = val;
    }
    __syncthreads();
  }

  // epilogue: buffer out(TT-1), then flush the 64 future outputs
  if (wid < 2 && lane == 0) {
    float o = lds_lin[(TT - 1) & 1][wid][0] + lds_lin[(TT - 1) & 1][wid][1] +
              blin_s;
    lds_outbuf[wid][63] = o;
  }
  __syncthreads();
  if (wid == 4 || wid == 5) {
    const int seq = wid - 4;
    out[(s0 + seq) * TT + TMAIN + lane] = lds_outbuf[seq][lane];
  }
}

extern "C" void kernel_launch(void* const* d_in, const int* in_sizes, int n_in,
                              void* d_out, int out_size, void* d_ws,
                              size_t ws_size, hipStream_t stream) {
  const float* input = (const float*)d_in[0];
  const float* Wi1 = (const float*)d_in[1];
  const float* Wh1 = (const float*)d_in[2];
  const float* bi1 = (const float*)d_in[3];
  const float* bh1 = (const float*)d_in[4];
  const float* Wi2 = (const float*)d_in[5];
  const float* Wh2 = (const float*)d_in[6];
  const float* bi2 = (const float*)d_in[7];
  const float* bh2 = (const float*)d_in[8];
  const float* Wlin = (const float*)d_in[9];
  const float* blin = (const float*)d_in[10];
  float* out = (float*)d_out;

  const int B = in_sizes[0] / TMAIN;  // 512
  lstm2_persistent<<<B / 2, 512, 0, stream>>>(input, Wi1, Wh1, bi1, bh1, Wi2,
                                              Wh2, bi2, bh2, Wlin, blin, out);
}

// Round 10
// 1392.226 us; speedup vs baseline: 10.6253x; 1.0009x over previous
//
#include <hip/hip_runtime.h>
#include <math.h>

#define HID 51
#define TMAIN 1024
#define FUT 64
#define TT (TMAIN + FUT)
#define RING 128   // h2 history ring depth (pow2)
#define RPAD 68    // ring row stride in floats (16B-aligned, bank-skewed)

typedef float v2f __attribute__((ext_vector_type(2)));

__device__ __forceinline__ float fast_sigmoid(float x) {
  return 1.0f / (1.0f + __expf(-x));
}
__device__ __forceinline__ float fast_tanh(float x) {
  // stable both directions: x>>0 -> 1, x<<0 -> -1
  return 1.0f - 2.0f / (__expf(2.0f * x) + 1.0f);
}

// Dual-sequence packed full-K dot: acc{A,B}[g] += sum_k w[g][k]*h{A,B}[k].
// float4 LDS reads; a4[12] touches h[48..51] (element 51 loaded but unused).
__device__ __forceinline__ void dot2x(const float* hA, const float* hB,
                                      const v2f (&w2)[2][25],
                                      const float (&w50)[2],
                                      float (&aA)[2], float (&aB)[2]) {
  const float4* a4 = reinterpret_cast<const float4*>(hA);
  const float4* b4 = reinterpret_cast<const float4*>(hB);
  v2f sA0 = {0.f, 0.f}, sA1 = {0.f, 0.f};
  v2f sB0 = {0.f, 0.f}, sB1 = {0.f, 0.f};
#pragma unroll
  for (int q = 0; q < 12; ++q) {
    float4 av = a4[q];
    float4 bv = b4[q];
    v2f alo = {av.x, av.y}, ahi = {av.z, av.w};
    v2f blo = {bv.x, bv.y}, bhi = {bv.z, bv.w};
    sA0 = __builtin_elementwise_fma(alo, w2[0][2 * q + 0], sA0);
    sB0 = __builtin_elementwise_fma(blo, w2[0][2 * q + 0], sB0);
    sA1 = __builtin_elementwise_fma(alo, w2[1][2 * q + 0], sA1);
    sB1 = __builtin_elementwise_fma(blo, w2[1][2 * q + 0], sB1);
    sA0 = __builtin_elementwise_fma(ahi, w2[0][2 * q + 1], sA0);
    sB0 = __builtin_elementwise_fma(bhi, w2[0][2 * q + 1], sB0);
    sA1 = __builtin_elementwise_fma(ahi, w2[1][2 * q + 1], sA1);
    sB1 = __builtin_elementwise_fma(bhi, w2[1][2 * q + 1], sB1);
  }
  float4 at = a4[12];
  float4 bt = b4[12];
  v2f alo = {at.x, at.y}, blo = {bt.x, bt.y};
  sA0 = __builtin_elementwise_fma(alo, w2[0][24], sA0);
  sB0 = __builtin_elementwise_fma(blo, w2[0][24], sB0);
  sA1 = __builtin_elementwise_fma(alo, w2[1][24], sA1);
  sB1 = __builtin_elementwise_fma(blo, w2[1][24], sB1);
  aA[0] = fmaf(at.z, w50[0], aA[0] + sA0.x + sA0.y);
  aB[0] = fmaf(bt.z, w50[0], aB[0] + sB0.x + sB0.y);
  aA[1] = fmaf(at.z, w50[1], aA[1] + sA1.x + sA1.y);
  aB[1] = fmaf(bt.z, w50[1], aB[1] + sB1.x + sB1.y);
}

// Half-K dual-seq dot: 13 float2 pairs starting at a pre-offset pointer.
// K2 waves' pair 12 multiplies {h[50],h[51]} by {w50,0}; h1[51] is kept 0.
__device__ __forceinline__ void dotH(const float* hA, const float* hB,
                                     const v2f (&w)[2][13],
                                     float (&aA)[2], float (&aB)[2]) {
  const float2* a2 = reinterpret_cast<const float2*>(hA);
  const float2* b2 = reinterpret_cast<const float2*>(hB);
  v2f sA0 = {0.f, 0.f}, sA1 = {0.f, 0.f};
  v2f sB0 = {0.f, 0.f}, sB1 = {0.f, 0.f};
#pragma unroll
  for (int p = 0; p < 13; ++p) {
    float2 av = a2[p], bv = b2[p];
    v2f a = {av.x, av.y}, b = {bv.x, bv.y};
    sA0 = __builtin_elementwise_fma(a, w[0][p], sA0);
    sB0 = __builtin_elementwise_fma(b, w[0][p], sB0);
    sA1 = __builtin_elementwise_fma(a, w[1][p], sA1);
    sB1 = __builtin_elementwise_fma(b, w[1][p], sB1);
  }
  aA[0] = sA0.x + sA0.y;
  aB[0] = sB0.x + sB0.y;
  aA[1] = sA1.x + sA1.y;
  aB[1] = sB1.x + sB1.y;
}

// One block = TWO sequences, 8 waves (R9 structure kept):
//   wid0,1: L1 cell, units [0,26)/[26,51)
//   wid2,3: Wh2 cell (L2), units [0,26)/[26,51)   [carry c2; feedback lin]
//   wid4,5: Wi2 K[26,51) partial (+bias2 fold)    [+ main-phase out flush]
//   wid6,7: Wi2 K[0,26)  partial
// Pipeline skew (1 barrier/interval): h1(k) | piK(k-1) | h2(k-2).
// R9 lesson: interval is LATENCY-bound (issue ~600cy of a ~2700cy-equiv
// interval; R7's issue cut was null, R8/R9 chain cuts paid). Registers
// (124 VGPR + ~102 AGPR) pin occupancy at 2 waves/SIMD, and skew-1 makes
// cross-barrier prefetch racy -> keep cutting the cell-wave chains:
//  - piS layout [par][seq][u][2g+kh]: L2-cell gathers its 4 gate partials
//    in ONE ds_read_b128 per seq (was 16 b32); bias2 folded into K2 writer.
//  - h1 [par][seq][64] / ring [RING][seq][RPAD]: per-seq state writes land
//    256/272B apart -> ds_write2-fusable, shared address math.
__global__ __launch_bounds__(512, 2)
void lstm2_persistent(const float* __restrict__ input,
                      const float* __restrict__ Wi1,
                      const float* __restrict__ Wh1,
                      const float* __restrict__ bi1,
                      const float* __restrict__ bh1,
                      const float* __restrict__ Wi2,
                      const float* __restrict__ Wh2,
                      const float* __restrict__ bi2,
                      const float* __restrict__ bh2,
                      const float* __restrict__ Wlin,
                      const float* __restrict__ blin,
                      float* __restrict__ out) {
  __shared__ __align__(16) float lds_x[2][TMAIN];        // [seq][t]
  __shared__ __align__(16) float lds_h1[2][2][64];       // [parity][seq][u]
  __shared__ __align__(16) float lds_piS[2][2][64][12];  // [par][seq][u][2g+kh]
  __shared__ __align__(16) float lds_h2h[RING][2][RPAD]; // [slot][seq][u]
  __shared__ __align__(16) float lds_wlin[64];
  __shared__ __align__(16) float lds_outbuf[2][64];      // feedback outputs
  __shared__ float lds_lin[2][2][2];                     // [par][seq][cellw]
  __shared__ float lds_fb[2];                            // out(1023) seed

  const int tid = threadIdx.x;
  const int s0 = blockIdx.x * 2;  // sequence pair
  const int wid = tid >> 6;       // 0..7
  const int lane = tid & 63;
  const int half = lane >> 5;   // 0: gates {i,f}, 1: gates {g,o}
  const int l5 = lane & 31;
  const int base = (wid & 1) * 26;
  const int nu = (wid & 1) ? 25 : 26;
  const bool act = l5 < nu;
  const int u = base + (act ? l5 : 0);  // clamped unit index
  const int g0 = half * 2;
  const int koff = (wid >= 6) ? 0 : 26;  // Wi2 K-half offset
  const int kh = (wid >= 6) ? 0 : 1;     // piS sub-slot

  // Stage inputs; zero h1 buffers (elems 51..63 too -> dotH pair-12 safe)
  // and ring slot RING-1 (h2(-1) = 0); stage wlin.
  for (int i = tid; i < TMAIN; i += 512) {
    lds_x[0][i] = input[s0 * TMAIN + i];
    lds_x[1][i] = input[(s0 + 1) * TMAIN + i];
  }
  if (tid < 64) {
    lds_h1[0][0][tid] = 0.0f;
    lds_h1[0][1][tid] = 0.0f;
    lds_h1[1][0][tid] = 0.0f;
    lds_h1[1][1][tid] = 0.0f;
    lds_wlin[tid] = (tid < HID) ? Wlin[tid] : 0.0f;
  }
  if (tid < 128) lds_h2h[RING - 1][tid >> 6][tid & 63] = 0.0f;

  // ---- weights ----
  v2f w2f[2][25];  // full rows (L1 / Wh2 cell waves)
  float w50f[2] = {0.f, 0.f};
  v2f w2h[2][13];  // half rows (Wi2 waves)
  float bias[2] = {0.f, 0.f};
  float wi1g[2] = {0.f, 0.f};
  float wlin_u = 0.0f;
  float cA = 0.0f, cB = 0.0f;  // cell states (L1 in wid01, L2 in wid23)

  if (wid < 4) {
    const float* Wsel = (wid < 2) ? Wh1 : Wh2;
#pragma unroll
    for (int g = 0; g < 2; ++g) {
      const float* row = Wsel + ((g0 + g) * HID + u) * HID;
#pragma unroll
      for (int p = 0; p < 25; ++p) {
        v2f t;
        t.x = row[2 * p + 0];
        t.y = row[2 * p + 1];
        w2f[g][p] = t;
      }
      w50f[g] = row[50];
    }
    if (wid < 2) {
#pragma unroll
      for (int g = 0; g < 2; ++g) {
        bias[g] = bi1[(g0 + g) * HID + u] + bh1[(g0 + g) * HID + u];
        wi1g[g] = Wi1[(g0 + g) * HID + u];
      }
    } else {
      wlin_u = Wlin[u];  // feedback-phase butterfly weight
    }
#pragma unroll
    for (int g = 0; g < 2; ++g) {
#pragma unroll
      for (int p = 0; p < 25; ++p) asm volatile("" : "+v"(w2f[g][p]));
      asm volatile("" : "+v"(w50f[g]), "+v"(bias[g]), "+v"(wi1g[g]));
    }
    asm volatile("" : "+v"(wlin_u));
  } else {
#pragma unroll
    for (int g = 0; g < 2; ++g) {
      const float* row = Wi2 + ((g0 + g) * HID + u) * HID + koff;
      if (koff == 0) {
#pragma unroll
        for (int p = 0; p < 13; ++p) {
          v2f t;
          t.x = row[2 * p + 0];
          t.y = row[2 * p + 1];
          w2h[g][p] = t;
        }
      } else {
#pragma unroll
        for (int p = 0; p < 12; ++p) {
          v2f t;
          t.x = row[2 * p + 0];
          t.y = row[2 * p + 1];
          w2h[g][p] = t;
        }
        v2f t;
        t.x = row[24];  // K=50
        t.y = 0.0f;     // pairs with h1[51] == 0
        w2h[g][12] = t;
      }
    }
    if (kh == 1) {  // K2 waves carry bias2 (folded into their piS writes)
#pragma unroll
      for (int g = 0; g < 2; ++g)
        bias[g] = bi2[(g0 + g) * HID + u] + bh2[(g0 + g) * HID + u];
    }
#pragma unroll
    for (int g = 0; g < 2; ++g) {
#pragma unroll
      for (int p = 0; p < 13; ++p) asm volatile("" : "+v"(w2h[g][p]));
      asm volatile("" : "+v"(bias[g]));
    }
  }
  const float blin_s = blin[0];

  __syncthreads();

  // =============== main-phase pipeline: one barrier per interval ========
  for (int k = 0; k <= TMAIN + 2; ++k) {
    if (wid < 2) {
      if (k < TMAIN) {
        // h1(k) = cell1(x(k), h1(k-1));  h1(m) lives in buffer (m+1)&1
        float xA = lds_x[0][k], xB = lds_x[1][k];
        float aA[2], aB[2];
#pragma unroll
        for (int g = 0; g < 2; ++g) {
          aA[g] = fmaf(xA, wi1g[g], bias[g]);
          aB[g] = fmaf(xB, wi1g[g], bias[g]);
        }
        dot2x(lds_h1[k & 1][0], lds_h1[k & 1][1], w2f, w50f, aA, aB);
        float pA0 = __shfl_xor(aA[0], 32), pA1 = __shfl_xor(aA[1], 32);
        float pB0 = __shfl_xor(aB[0], 32), pB1 = __shfl_xor(aB[1], 32);
        float giA = half ? pA0 : aA[0], gfA = half ? pA1 : aA[1];
        float ggA = half ? aA[0] : pA0, goA = half ? aA[1] : pA1;
        float giB = half ? pB0 : aB[0], gfB = half ? pB1 : aB[1];
        float ggB = half ? aB[0] : pB0, goB = half ? aB[1] : pB1;
        cA = fast_sigmoid(gfA) * cA + fast_sigmoid(giA) * fast_tanh(ggA);
        cB = fast_sigmoid(gfB) * cB + fast_sigmoid(giB) * fast_tanh(ggB);
        float hA = fast_sigmoid(goA) * fast_tanh(cA);
        float hB = fast_sigmoid(goB) * fast_tanh(cB);
        if (act && half == 0) {
          lds_h1[(k + 1) & 1][0][u] = hA;
          lds_h1[(k + 1) & 1][1][u] = hB;
        }
      }
    } else if (wid < 4) {
      if (k >= 2 && k <= TMAIN + 1) {
        // h2(m2) = cell2(piS(m2) + Wh2 @ h2(m2-1)), bias pre-folded in piS
        const int m2 = k - 2;
        const int pm = m2 & 1;
        float4 vA = *reinterpret_cast<const float4*>(&lds_piS[pm][0][u][2 * g0]);
        float4 vB = *reinterpret_cast<const float4*>(&lds_piS[pm][1][u][2 * g0]);
        float aA[2], aB[2];
        aA[0] = vA.x + vA.y;
        aA[1] = vA.z + vA.w;
        aB[0] = vB.x + vB.y;
        aB[1] = vB.z + vB.w;
        dot2x(&lds_h2h[(m2 - 1) & (RING - 1)][0][0],
              &lds_h2h[(m2 - 1) & (RING - 1)][1][0], w2f, w50f, aA, aB);
        float pA0 = __shfl_xor(aA[0], 32), pA1 = __shfl_xor(aA[1], 32);
        float pB0 = __shfl_xor(aB[0], 32), pB1 = __shfl_xor(aB[1], 32);
        float giA = half ? pA0 : aA[0], gfA = half ? pA1 : aA[1];
        float ggA = half ? aA[0] : pA0, goA = half ? aA[1] : pA1;
        float giB = half ? pB0 : aB[0], gfB = half ? pB1 : aB[1];
        float ggB = half ? aB[0] : pB0, goB = half ? aB[1] : pB1;
        cA = fast_sigmoid(gfA) * cA + fast_sigmoid(giA) * fast_tanh(ggA);
        cB = fast_sigmoid(gfB) * cB + fast_sigmoid(giB) * fast_tanh(ggB);
        float hA = fast_sigmoid(goA) * fast_tanh(cA);
        float hB = fast_sigmoid(goB) * fast_tanh(cB);
        if (act && half == 0) {
          lds_h2h[m2 & (RING - 1)][0][u] = hA;
          lds_h2h[m2 & (RING - 1)][1][u] = hB;
        }
      }
    } else {
      if (k >= 1 && k <= TMAIN) {
        // piS(k-1) partial: Wi2[:, koff:+26] @ h1(k-1)[koff:] (+bias2 on K2)
        float aA[2], aB[2];
        dotH(&lds_h1[k & 1][0][koff], &lds_h1[k & 1][1][koff], w2h, aA, aB);
        const int pm = (k - 1) & 1;
        if (act) {
          if (kh == 1) {
            aA[0] += bias[0];
            aA[1] += bias[1];
            aB[0] += bias[0];
            aB[1] += bias[1];
          }
          lds_piS[pm][0][u][2 * (g0 + 0) + kh] = aA[0];
          lds_piS[pm][0][u][2 * (g0 + 1) + kh] = aA[1];
          lds_piS[pm][1][u][2 * (g0 + 0) + kh] = aB[0];
          lds_piS[pm][1][u][2 * (g0 + 1) + kh] = aB[1];
        }
      }
      // Deferred linear head: every 64 intervals, waves 4,5 emit 64 outs
      // each (chunk c=k-66; h2(c+63) landed at interval c+65; writer this
      // interval touches slot (c+64)&127 -- disjoint from read slots).
      if (wid < 6 && k >= 66 && ((k - 66) & 63) == 0) {
        const int c = k - 66;
        const int seq = wid - 4;
        const int m = c + lane;
        const float* r = &lds_h2h[m & (RING - 1)][seq][0];
        float o0 = 0.f, o1 = 0.f;
#pragma unroll
        for (int j = 0; j < 48; j += 2) {
          o0 = fmaf(lds_wlin[j], r[j], o0);
          o1 = fmaf(lds_wlin[j + 1], r[j + 1], o1);
        }
        o0 = fmaf(lds_wlin[48], r[48], o0);
        o1 = fmaf(lds_wlin[49], r[49], o1);
        o0 = fmaf(lds_wlin[50], r[50], o0);
        float o = o0 + o1 + blin_s;
        out[(s0 + seq) * TT + m] = o;
        if (m == TMAIN - 1) lds_fb[seq] = o;  // feedback seed
      }
    }
    __syncthreads();
  }

  // =============== feedback phase: 3 sub-phases, serial ================
  for (int t = TMAIN; t < TT; ++t) {
    float phA[2] = {0.f, 0.f}, phB[2] = {0.f, 0.f};
    // --- A: L1 cell with feedback x; cell waves pre-dot Wh2 @ h2(t-1) ---
    if (wid < 2) {
      float oA, oB;
      if (t == TMAIN) {
        oA = lds_fb[0];
        oB = lds_fb[1];
      } else {
        oA = lds_lin[(t - 1) & 1][0][0] + lds_lin[(t - 1) & 1][0][1] + blin_s;
        oB = lds_lin[(t - 1) & 1][1][0] + lds_lin[(t - 1) & 1][1][1] + blin_s;
        if (lane == 0) {  // buffer future outputs; flushed in epilogue
          if (wid == 0) lds_outbuf[0][t - 1 - TMAIN] = oA;
          else          lds_outbuf[1][t - 1 - TMAIN] = oB;
        }
      }
      float aA[2], aB[2];
#pragma unroll
      for (int g = 0; g < 2; ++g) {
        aA[g] = fmaf(oA, wi1g[g], bias[g]);
        aB[g] = fmaf(oB, wi1g[g], bias[g]);
      }
      dot2x(lds_h1[t & 1][0], lds_h1[t & 1][1], w2f, w50f, aA, aB);
      float pA0 = __shfl_xor(aA[0], 32), pA1 = __shfl_xor(aA[1], 32);
      float pB0 = __shfl_xor(aB[0], 32), pB1 = __shfl_xor(aB[1], 32);
      float giA = half ? pA0 : aA[0], gfA = half ? pA1 : aA[1];
      float ggA = half ? aA[0] : pA0, goA = half ? aA[1] : pA1;
      float giB = half ? pB0 : aB[0], gfB = half ? pB1 : aB[1];
      float ggB = half ? aB[0] : pB0, goB = half ? aB[1] : pB1;
      cA = fast_sigmoid(gfA) * cA + fast_sigmoid(giA) * fast_tanh(ggA);
      cB = fast_sigmoid(gfB) * cB + fast_sigmoid(giB) * fast_tanh(ggB);
      float hA = fast_sigmoid(goA) * fast_tanh(cA);
      float hB = fast_sigmoid(goB) * fast_tanh(cB);
      if (act && half == 0) {
        lds_h1[(t + 1) & 1][0][u] = hA;
        lds_h1[(t + 1) & 1][1][u] = hB;
      }
    } else if (wid < 4) {
      dot2x(&lds_h2h[(t - 1) & (RING - 1)][0][0],
            &lds_h2h[(t - 1) & (RING - 1)][1][0], w2f, w50f, phA, phB);
    }
    __syncthreads();
    // --- B: piS halves from h1(t) ---
    if (wid >= 4) {
      float aA[2], aB[2];
      dotH(&lds_h1[(t + 1) & 1][0][koff], &lds_h1[(t + 1) & 1][1][koff], w2h,
           aA, aB);
      const int pm = t & 1;
      if (act) {
        if (kh == 1) {
          aA[0] += bias[0];
          aA[1] += bias[1];
          aB[0] += bias[0];
          aB[1] += bias[1];
        }
        lds_piS[pm][0][u][2 * (g0 + 0) + kh] = aA[0];
        lds_piS[pm][0][u][2 * (g0 + 1) + kh] = aA[1];
        lds_piS[pm][1][u][2 * (g0 + 0) + kh] = aB[0];
        lds_piS[pm][1][u][2 * (g0 + 1) + kh] = aB[1];
      }
    }
    __syncthreads();
    // --- C: L2 cell + linear head (butterfly on cell waves here) ---
    if (wid >= 2 && wid < 4) {
      const int pm = t & 1;
      float4 vA = *reinterpret_cast<const float4*>(&lds_piS[pm][0][u][2 * g0]);
      float4 vB = *reinterpret_cast<const float4*>(&lds_piS[pm][1][u][2 * g0]);
      float aA[2], aB[2];
      aA[0] = vA.x + vA.y + phA[0];
      aA[1] = vA.z + vA.w + phA[1];
      aB[0] = vB.x + vB.y + phB[0];
      aB[1] = vB.z + vB.w + phB[1];
      float pA0 = __shfl_xor(aA[0], 32), pA1 = __shfl_xor(aA[1], 32);
      float pB0 = __shfl_xor(aB[0], 32), pB1 = __shfl_xor(aB[1], 32);
      float giA = half ? pA0 : aA[0], gfA = half ? pA1 : aA[1];
      float ggA = half ? aA[0] : pA0, goA = half ? aA[1] : pA1;
      float giB = half ? pB0 : aB[0], gfB = half ? pB1 : aB[1];
      float ggB = half ? aB[0] : pB0, goB = half ? aB[1] : pB1;
      cA = fast_sigmoid(gfA) * cA + fast_sigmoid(giA) * fast_tanh(ggA);
      cB = fast_sigmoid(gfB) * cB + fast_sigmoid(giB) * fast_tanh(ggB);
      float hA = fast_sigmoid(goA) * fast_tanh(cA);
      float hB = fast_sigmoid(goB) * fast_tanh(cB);
      float val = 0.0f;
      if (act) {
        if (half == 0) {
          lds_h2h[t & (RING - 1)][0][u] = hA;
          val = wlin_u * hA;
        } else {
          lds_h2h[t & (RING - 1)][1][u] = hB;
          val = wlin_u * hB;
        }
      }
#pragma unroll
      for (int off = 16; off >= 1; off >>= 1) val += __shfl_xor(val, off);
      if (lane == 0) lds_lin[t & 1][0][wid - 2] = val;
      if (lane == 32) lds_lin[t & 1][1][wid - 2] = val;
    }
    __syncthreads();
  }

  // epilogue: buffer out(TT-1), then flush the 64 future outputs
  if (wid < 2 && lane == 0) {
    float o = lds_lin[(TT - 1) & 1][wid][0] + lds_lin[(TT - 1) & 1][wid][1] +
              blin_s;
    lds_outbuf[wid][63] = o;
  }
  __syncthreads();
  if (wid == 4 || wid == 5) {
    const int seq = wid - 4;
    out[(s0 + seq) * TT + TMAIN + lane] = lds_outbuf[seq][lane];
  }
}

extern "C" void kernel_launch(void* const* d_in, const int* in_sizes, int n_in,
                              void* d_out, int out_size, void* d_ws,
                              size_t ws_size, hipStream_t stream) {
  const float* input = (const float*)d_in[0];
  const float* Wi1 = (const float*)d_in[1];
  const float* Wh1 = (const float*)d_in[2];
  const float* bi1 = (const float*)d_in[3];
  const float* bh1 = (const float*)d_in[4];
  const float* Wi2 = (const float*)d_in[5];
  const float* Wh2 = (const float*)d_in[6];
  const float* bi2 = (const float*)d_in[7];
  const float* bh2 = (const float*)d_in[8];
  const float* Wlin = (const float*)d_in[9];
  const float* blin = (const float*)d_in[10];
  float* out = (float*)d_out;

  const int B = in_sizes[0] / TMAIN;  // 512
  lstm2_persistent<<<B / 2, 512, 0, stream>>>(input, Wi1, Wh1, bi1, bh1, Wi2,
                                              Wh2, bi2, bh2, Wlin, blin, out);
}